// Round 1
// baseline (5424.494 us; speedup 1.0000x reference)
//
#include <hip/hip_runtime.h>
#include <math.h>

#define N_NODES 10000
#define E_EDGES 160000
#define DIM     256
#define R_REL   237
#define L_LAYERS 6
#define B_BATCH 128
#define K_BATCH 33
#define K13     3328   // 13*256
#define EPS_STD 1e-6f
#define EPS_LN  1e-5f

// ---------------- CSR build ----------------
__global__ void hist_kernel(const int* __restrict__ dst, int* __restrict__ deg) {
    int e = blockIdx.x * blockDim.x + threadIdx.x;
    if (e < E_EDGES) atomicAdd(&deg[dst[e]], 1);
}

// single-block exclusive scan of deg_in -> offs (and cursor copy), plus sum of log(deg_in+1)
__global__ void scan_kernel(const int* __restrict__ deg_in, int* __restrict__ offs,
                            int* __restrict__ cursor, float* __restrict__ sum_log) {
    __shared__ int   part[1024];
    __shared__ float slog[1024];
    int t = threadIdx.x;
    const int CH = 10; // 1024*10 >= 10000
    int base = t * CH;
    int lsum = 0; float ls = 0.f;
    for (int j = 0; j < CH; j++) {
        int i = base + j;
        if (i < N_NODES) { int d = deg_in[i]; lsum += d; ls += logf((float)(d + 1)); }
    }
    part[t] = lsum; slog[t] = ls;
    __syncthreads();
    for (int off = 1; off < 1024; off <<= 1) {
        int v = (t >= off) ? part[t - off] : 0;
        __syncthreads();
        part[t] += v;
        __syncthreads();
    }
    int run = part[t] - lsum; // exclusive base for this thread's chunk
    for (int j = 0; j < CH; j++) {
        int i = base + j;
        if (i < N_NODES) { offs[i] = run; cursor[i] = run; run += deg_in[i]; }
    }
    __syncthreads();
    for (int off = 512; off > 0; off >>= 1) {
        if (t < off) slog[t] += slog[t + off];
        __syncthreads();
    }
    if (t == 0) sum_log[0] = slog[0];
}

__global__ void fill_kernel(const int* __restrict__ src, const int* __restrict__ dst,
                            const int* __restrict__ et, int* __restrict__ cursor,
                            int* __restrict__ csr_src, int* __restrict__ csr_et) {
    int e = blockIdx.x * blockDim.x + threadIdx.x;
    if (e < E_EDGES) {
        int d = dst[e];
        int p = atomicAdd(&cursor[d], 1);
        csr_src[p] = src[e];
        csr_et[p]  = et[e];
    }
}

__global__ void scales_kernel(const int* __restrict__ deg_in, const float* __restrict__ sum_log,
                              float* __restrict__ s1, float* __restrict__ s2) {
    int i = blockIdx.x * blockDim.x + threadIdx.x;
    if (i < N_NODES) {
        float mean = sum_log[0] * (1.0f / (float)N_NODES);
        float sc = logf((float)(deg_in[i] + 1)) / mean;
        s1[i] = sc;
        s2[i] = 1.0f / fmaxf(sc, 0.01f);
    }
}

// ---------------- per-layer aggregation: one wave per node ----------------
__global__ void agg_kernel(const float* __restrict__ x, const float* __restrict__ rel,
                           const int* __restrict__ offs, const int* __restrict__ deg_in,
                           const int* __restrict__ csr_src, const int* __restrict__ csr_et,
                           float* __restrict__ feats) {
    int wid  = threadIdx.x >> 6;
    int lane = threadIdx.x & 63;
    int node = blockIdx.x * 4 + wid;
    if (node >= N_NODES) return;
    int off = offs[node];
    int dc  = deg_in[node];
    const float4* xv4 = (const float4*)x;
    const float4* rv4 = (const float4*)rel;
    float sx=0,sy=0,sz=0,sw=0, qx=0,qy=0,qz=0,qw=0;
    float mxx=-INFINITY,mxy=-INFINITY,mxz=-INFINITY,mxw=-INFINITY;
    float mnx= INFINITY,mny= INFINITY,mnz= INFINITY,mnw= INFINITY;
    for (int idx = off; idx < off + dc; idx++) {
        int s  = csr_src[idx];
        int et = csr_et[idx];
        float4 xv = xv4[(size_t)s * 64 + lane];
        float4 rv = rv4[(size_t)et * 64 + lane];
        float mx_ = xv.x * rv.x, my_ = xv.y * rv.y, mz_ = xv.z * rv.z, mw_ = xv.w * rv.w;
        sx += mx_; sy += my_; sz += mz_; sw += mw_;
        qx += mx_*mx_; qy += my_*my_; qz += mz_*mz_; qw += mw_*mw_;
        mxx = fmaxf(mxx, mx_); mxy = fmaxf(mxy, my_); mxz = fmaxf(mxz, mz_); mxw = fmaxf(mxw, mw_);
        mnx = fminf(mnx, mx_); mny = fminf(mny, my_); mnz = fminf(mnz, mz_); mnw = fminf(mnw, mw_);
    }
    { // self loop message = x (no rel multiply)
        float4 xv = xv4[(size_t)node * 64 + lane];
        sx += xv.x; sy += xv.y; sz += xv.z; sw += xv.w;
        qx += xv.x*xv.x; qy += xv.y*xv.y; qz += xv.z*xv.z; qw += xv.w*xv.w;
        mxx = fmaxf(mxx, xv.x); mxy = fmaxf(mxy, xv.y); mxz = fmaxf(mxz, xv.z); mxw = fmaxf(mxw, xv.w);
        mnx = fminf(mnx, xv.x); mny = fminf(mny, xv.y); mnz = fminf(mnz, xv.z); mnw = fminf(mnw, xv.w);
    }
    float inv = 1.0f / (float)(dc + 1);
    float4 mean = {sx*inv, sy*inv, sz*inv, sw*inv};
    float4 stdv = {
        sqrtf(fmaxf(qx*inv - mean.x*mean.x, EPS_STD)),
        sqrtf(fmaxf(qy*inv - mean.y*mean.y, EPS_STD)),
        sqrtf(fmaxf(qz*inv - mean.z*mean.z, EPS_STD)),
        sqrtf(fmaxf(qw*inv - mean.w*mean.w, EPS_STD))};
    float4* f4 = (float4*)(feats + (size_t)node * 1024);
    f4[lane]        = mean;
    f4[64  + lane]  = make_float4(mxx,mxy,mxz,mxw);
    f4[128 + lane]  = make_float4(mnx,mny,mnz,mnw);
    f4[192 + lane]  = stdv;
}

// ---------------- per-layer GEMM + bias + LN + relu + residual ----------------
// C(64 rows x 256 cols) per block; 256 threads: cq=tid&63 (col base), rg=tid>>6 (row group)
// thread owns rows [rg*16, rg*16+16) x cols {cq, cq+64, cq+128, cq+192}
__launch_bounds__(256)
__global__ void gemm_kernel(const float* __restrict__ feats, const float* __restrict__ s1a,
                            const float* __restrict__ s2a, const float* __restrict__ xin,
                            const float* __restrict__ W, const float* __restrict__ bvec,
                            const float* __restrict__ gvec, const float* __restrict__ bevec,
                            float* __restrict__ xout) {
    __shared__ float As[64 * 33];
    int tid = threadIdx.x;
    int cq = tid & 63;
    int rg = tid >> 6;
    int i0 = blockIdx.x * 64;
    float acc[16][4];
    #pragma unroll
    for (int m = 0; m < 16; m++) { acc[m][0]=0.f; acc[m][1]=0.f; acc[m][2]=0.f; acc[m][3]=0.f; }

    for (int k0 = 0; k0 < K13; k0 += 32) {
        __syncthreads();
        #pragma unroll
        for (int q = 0; q < 8; q++) {
            int idx = tid + 256 * q;
            int m = idx >> 5, kk = idx & 31;
            int i = i0 + m;
            float v = 0.f;
            if (i < N_NODES) {
                int k = k0 + kk;
                if (k < 3072) {
                    int f = k / 3; int s = k - f * 3;
                    float fv = feats[(size_t)i * 1024 + f];
                    float scl = (s == 0) ? 1.0f : (s == 1 ? s1a[i] : s2a[i]);
                    v = fv * scl;
                } else {
                    v = xin[(size_t)i * 256 + (k - 3072)];
                }
            }
            As[m * 33 + kk] = v;
        }
        __syncthreads();
        #pragma unroll
        for (int kk = 0; kk < 32; kk++) {
            int k = k0 + kk;
            float w0 = W[(size_t)k * 256 + cq];
            float w1 = W[(size_t)k * 256 + cq + 64];
            float w2 = W[(size_t)k * 256 + cq + 128];
            float w3 = W[(size_t)k * 256 + cq + 192];
            #pragma unroll
            for (int m = 0; m < 16; m++) {
                float a = As[(rg * 16 + m) * 33 + kk];
                acc[m][0] += a * w0; acc[m][1] += a * w1;
                acc[m][2] += a * w2; acc[m][3] += a * w3;
            }
        }
    }

    float b0 = bvec[cq], b1 = bvec[cq+64], b2 = bvec[cq+128], b3 = bvec[cq+192];
    float g0 = gvec[cq], g1 = gvec[cq+64], g2 = gvec[cq+128], g3 = gvec[cq+192];
    float e0 = bevec[cq], e1 = bevec[cq+64], e2 = bevec[cq+128], e3 = bevec[cq+192];
    for (int m = 0; m < 16; m++) {
        int row = i0 + rg * 16 + m;        // wave-uniform
        if (row >= N_NODES) continue;
        float h0 = acc[m][0] + b0, h1 = acc[m][1] + b1;
        float h2 = acc[m][2] + b2, h3 = acc[m][3] + b3;
        float psum = h0 + h1 + h2 + h3;
        float psq  = h0*h0 + h1*h1 + h2*h2 + h3*h3;
        #pragma unroll
        for (int off = 1; off < 64; off <<= 1) {
            psum += __shfl_xor(psum, off);
            psq  += __shfl_xor(psq, off);
        }
        float mu  = psum * (1.0f / 256.0f);
        float var = psq * (1.0f / 256.0f) - mu * mu;
        float rs  = rsqrtf(var + EPS_LN);
        const float* xr = xin + (size_t)row * 256;
        float* orow = xout + (size_t)row * 256;
        float o0 = fmaxf((h0 - mu) * rs * g0 + e0, 0.f) + xr[cq];
        float o1 = fmaxf((h1 - mu) * rs * g1 + e1, 0.f) + xr[cq + 64];
        float o2 = fmaxf((h2 - mu) * rs * g2 + e2, 0.f) + xr[cq + 128];
        float o3 = fmaxf((h3 - mu) * rs * g3 + e3, 0.f) + xr[cq + 192];
        orow[cq] = o0; orow[cq + 64] = o1; orow[cq + 128] = o2; orow[cq + 192] = o3;
    }
}

// ---------------- final scoring ----------------
__global__ void score_kernel(const float* __restrict__ x, const float* __restrict__ remb,
                             const int* __restrict__ batch, float* __restrict__ out) {
    int wid = threadIdx.x >> 6, lane = threadIdx.x & 63;
    int g = blockIdx.x * 4 + wid;
    if (g >= B_BATCH * K_BATCH) return;
    int si = batch[g * 3 + 0], ri = batch[g * 3 + 1], ti = batch[g * 3 + 2];
    const float4* xs = (const float4*)(x + (size_t)si * 256);
    const float4* xr = (const float4*)(remb + (size_t)ri * 256);
    const float4* xt = (const float4*)(x + (size_t)ti * 256);
    float4 a = xs[lane], r = xr[lane], t = xt[lane];
    float p = a.x*r.x*t.x + a.y*r.y*t.y + a.z*r.z*t.z + a.w*r.w*t.w;
    #pragma unroll
    for (int off = 1; off < 64; off <<= 1) p += __shfl_xor(p, off);
    if (lane == 0) out[g] = p;
}

extern "C" void kernel_launch(void* const* d_in, const int* in_sizes, int n_in,
                              void* d_out, int out_size, void* d_ws, size_t ws_size,
                              hipStream_t stream) {
    const float* x_in     = (const float*)d_in[0];
    const float* rel_embs = (const float*)d_in[1];
    const float* Ws       = (const float*)d_in[2];
    const float* bs       = (const float*)d_in[3];
    const float* ln_s     = (const float*)d_in[4];
    const float* ln_b     = (const float*)d_in[5];
    const float* remb     = (const float*)d_in[6];
    const int*   eidx     = (const int*)d_in[7];
    const int*   etype    = (const int*)d_in[8];
    const int*   batch    = (const int*)d_in[9];
    float* out = (float*)d_out;

    char* w = (char*)d_ws;
    size_t o = 0;
    auto alloc = [&](size_t bytes) { void* p = w + o; o += (bytes + 255) & ~255ull; return p; };
    int*   deg_in  = (int*)  alloc((size_t)N_NODES * 4);
    int*   offs    = (int*)  alloc((size_t)N_NODES * 4);
    int*   cursor  = (int*)  alloc((size_t)N_NODES * 4);
    float* s1      = (float*)alloc((size_t)N_NODES * 4);
    float* s2      = (float*)alloc((size_t)N_NODES * 4);
    float* sum_log = (float*)alloc(256);
    int*   csr_src = (int*)  alloc((size_t)E_EDGES * 4);
    int*   csr_et  = (int*)  alloc((size_t)E_EDGES * 4);
    float* feats   = (float*)alloc((size_t)N_NODES * 1024 * 4);
    float* xb0     = (float*)alloc((size_t)N_NODES * 256 * 4);
    float* xb1     = (float*)alloc((size_t)N_NODES * 256 * 4);

    const int* src  = eidx;
    const int* dstp = eidx + E_EDGES;

    hipMemsetAsync(deg_in, 0, (size_t)N_NODES * 4, stream);
    hist_kernel<<<(E_EDGES + 255) / 256, 256, 0, stream>>>(dstp, deg_in);
    scan_kernel<<<1, 1024, 0, stream>>>(deg_in, offs, cursor, sum_log);
    fill_kernel<<<(E_EDGES + 255) / 256, 256, 0, stream>>>(src, dstp, etype, cursor, csr_src, csr_et);
    scales_kernel<<<(N_NODES + 255) / 256, 256, 0, stream>>>(deg_in, sum_log, s1, s2);
    hipMemcpyAsync(xb0, x_in, (size_t)N_NODES * 256 * 4, hipMemcpyDeviceToDevice, stream);

    float* xc = xb0; float* xn = xb1;
    for (int l = 0; l < L_LAYERS; l++) {
        agg_kernel<<<(N_NODES + 3) / 4, 256, 0, stream>>>(
            xc, rel_embs + (size_t)l * R_REL * 256, offs, deg_in, csr_src, csr_et, feats);
        gemm_kernel<<<(N_NODES + 63) / 64, 256, 0, stream>>>(
            feats, s1, s2, xc, Ws + (size_t)l * K13 * 256,
            bs + (size_t)l * 256, ln_s + (size_t)l * 256, ln_b + (size_t)l * 256, xn);
        float* t = xc; xc = xn; xn = t;
    }
    score_kernel<<<(B_BATCH * K_BATCH + 3) / 4, 256, 0, stream>>>(xc, remb, batch, out);
}

// Round 2
// 871.650 us; speedup vs baseline: 6.2232x; 6.2232x over previous
//
#include <hip/hip_runtime.h>
#include <math.h>

typedef __attribute__((ext_vector_type(8))) _Float16 half8;
typedef __attribute__((ext_vector_type(4))) _Float16 half4;
typedef __attribute__((ext_vector_type(4))) float    floatx4;

#define N_NODES 10000
#define M_PAD   10048      // 157 * 64
#define E_EDGES 160000
#define DIM     256
#define R_REL   237
#define L_LAYERS 6
#define B_BATCH 128
#define K_BATCH 33
#define K13     3328       // 13*256
#define EPS_STD 1e-6f
#define EPS_LN  1e-5f

// async global->LDS, 16B per lane; LDS dest = wave-uniform base + lane*16
__device__ __forceinline__ void gload16(const void* g, void* lds) {
    __builtin_amdgcn_global_load_lds(
        (const __attribute__((address_space(1))) unsigned int*)g,
        (__attribute__((address_space(3))) unsigned int*)lds, 16, 0, 0);
}

// ---------------- CSR build ----------------
__global__ void hist_kernel(const int* __restrict__ dst, int* __restrict__ deg) {
    int e = blockIdx.x * blockDim.x + threadIdx.x;
    if (e < E_EDGES) atomicAdd(&deg[dst[e]], 1);
}

__global__ void scan_kernel(const int* __restrict__ deg_in, int* __restrict__ offs,
                            int* __restrict__ cursor, float* __restrict__ sum_log) {
    __shared__ int   part[1024];
    __shared__ float slog[1024];
    int t = threadIdx.x;
    const int CH = 10;
    int base = t * CH;
    int lsum = 0; float ls = 0.f;
    for (int j = 0; j < CH; j++) {
        int i = base + j;
        if (i < N_NODES) { int d = deg_in[i]; lsum += d; ls += logf((float)(d + 1)); }
    }
    part[t] = lsum; slog[t] = ls;
    __syncthreads();
    for (int off = 1; off < 1024; off <<= 1) {
        int v = (t >= off) ? part[t - off] : 0;
        __syncthreads();
        part[t] += v;
        __syncthreads();
    }
    int run = part[t] - lsum;
    for (int j = 0; j < CH; j++) {
        int i = base + j;
        if (i < N_NODES) { offs[i] = run; cursor[i] = run; run += deg_in[i]; }
    }
    __syncthreads();
    for (int off = 512; off > 0; off >>= 1) {
        if (t < off) slog[t] += slog[t + off];
        __syncthreads();
    }
    if (t == 0) sum_log[0] = slog[0];
}

__global__ void fill_kernel(const int* __restrict__ src, const int* __restrict__ dst,
                            const int* __restrict__ et, int* __restrict__ cursor,
                            int* __restrict__ csr_src, int* __restrict__ csr_et) {
    int e = blockIdx.x * blockDim.x + threadIdx.x;
    if (e < E_EDGES) {
        int d = dst[e];
        int p = atomicAdd(&cursor[d], 1);
        csr_src[p] = src[e];
        csr_et[p]  = et[e];
    }
}

__global__ void scales_kernel(const int* __restrict__ deg_in, const float* __restrict__ sum_log,
                              float* __restrict__ s1, float* __restrict__ s2) {
    int i = blockIdx.x * blockDim.x + threadIdx.x;
    if (i < N_NODES) {
        float mean = sum_log[0] * (1.0f / (float)N_NODES);
        float sc = logf((float)(deg_in[i] + 1)) / mean;
        s1[i] = sc;
        s2[i] = 1.0f / fmaxf(sc, 0.01f);
    }
}

// -------- W transpose + fp16 pack: Wt[l][n][k] = W[l][k][n] --------
__global__ void wt_kernel(const float* __restrict__ Ws, _Float16* __restrict__ Wt) {
    int idx = blockIdx.x * 256 + threadIdx.x;
    const int TOT = L_LAYERS * 256 * K13;
    if (idx >= TOT) return;
    int l = idx / (256 * K13);
    int r = idx - l * (256 * K13);
    int n = r / K13, k = r - n * K13;
    Wt[idx] = (_Float16)Ws[(size_t)l * K13 * 256 + (size_t)k * 256 + n];
}

// ---- aggregation: one wave per node; emits fp16 A row (scale-folded, k-interleaved) ----
__global__ void agg_kernel(const float* __restrict__ x, const float* __restrict__ rel,
                           const int* __restrict__ offs, const int* __restrict__ deg_in,
                           const int* __restrict__ csr_src, const int* __restrict__ csr_et,
                           const float* __restrict__ s1a, const float* __restrict__ s2a,
                           _Float16* __restrict__ Ah) {
    int wid  = threadIdx.x >> 6;
    int lane = threadIdx.x & 63;
    int node = blockIdx.x * 4 + wid;
    if (node >= N_NODES) return;
    int off = offs[node];
    int dc  = deg_in[node];
    const float4* xv4 = (const float4*)x;
    const float4* rv4 = (const float4*)rel;
    float sx=0,sy=0,sz=0,sw=0, qx=0,qy=0,qz=0,qw=0;
    float mxx=-INFINITY,mxy=-INFINITY,mxz=-INFINITY,mxw=-INFINITY;
    float mnx= INFINITY,mny= INFINITY,mnz= INFINITY,mnw= INFINITY;
    for (int idx = off; idx < off + dc; idx++) {
        int s  = csr_src[idx];
        int et = csr_et[idx];
        float4 xv = xv4[(size_t)s * 64 + lane];
        float4 rv = rv4[(size_t)et * 64 + lane];
        float mx_ = xv.x * rv.x, my_ = xv.y * rv.y, mz_ = xv.z * rv.z, mw_ = xv.w * rv.w;
        sx += mx_; sy += my_; sz += mz_; sw += mw_;
        qx += mx_*mx_; qy += my_*my_; qz += mz_*mz_; qw += mw_*mw_;
        mxx = fmaxf(mxx, mx_); mxy = fmaxf(mxy, my_); mxz = fmaxf(mxz, mz_); mxw = fmaxf(mxw, mw_);
        mnx = fminf(mnx, mx_); mny = fminf(mny, my_); mnz = fminf(mnz, mz_); mnw = fminf(mnw, mw_);
    }
    float4 xself = xv4[(size_t)node * 64 + lane];
    sx += xself.x; sy += xself.y; sz += xself.z; sw += xself.w;
    qx += xself.x*xself.x; qy += xself.y*xself.y; qz += xself.z*xself.z; qw += xself.w*xself.w;
    mxx = fmaxf(mxx, xself.x); mxy = fmaxf(mxy, xself.y); mxz = fmaxf(mxz, xself.z); mxw = fmaxf(mxw, xself.w);
    mnx = fminf(mnx, xself.x); mny = fminf(mny, xself.y); mnz = fminf(mnz, xself.z); mnw = fminf(mnw, xself.w);

    float inv = 1.0f / (float)(dc + 1);
    float4 mean = {sx*inv, sy*inv, sz*inv, sw*inv};
    float4 mx = {mxx,mxy,mxz,mxw};
    float4 mn = {mnx,mny,mnz,mnw};
    float4 sd = {
        sqrtf(fmaxf(qx*inv - mean.x*mean.x, EPS_STD)),
        sqrtf(fmaxf(qy*inv - mean.y*mean.y, EPS_STD)),
        sqrtf(fmaxf(qz*inv - mean.z*mean.z, EPS_STD)),
        sqrtf(fmaxf(qw*inv - mean.w*mean.w, EPS_STD))};

    float s1v = s1a[node], s2v = s2a[node];
    half4* outp = (half4*)(Ah + (size_t)node * K13);
    // A col layout: k = (t*256+d)*3 + s  (t=feat type, d=dim, s=scale idx), then x at 3072+
    #pragma unroll
    for (int t = 0; t < 4; t++) {
        float4 v = (t == 0) ? mean : (t == 1 ? mx : (t == 2 ? mn : sd));
        int base = t * 192 + 3 * lane;   // half4 index: (t*768 + 12*lane)/4
        half4 h0 = { (_Float16)v.x, (_Float16)(v.x*s1v), (_Float16)(v.x*s2v), (_Float16)v.y };
        half4 h1 = { (_Float16)(v.y*s1v), (_Float16)(v.y*s2v), (_Float16)v.z, (_Float16)(v.z*s1v) };
        half4 h2 = { (_Float16)(v.z*s2v), (_Float16)v.w, (_Float16)(v.w*s1v), (_Float16)(v.w*s2v) };
        outp[base] = h0; outp[base+1] = h1; outp[base+2] = h2;
    }
    half4 hx = { (_Float16)xself.x, (_Float16)xself.y, (_Float16)xself.z, (_Float16)xself.w };
    outp[768 + lane] = hx;
}

// ---------------- fp16 MFMA GEMM + fused bias/LN/relu/residual ----------------
// block: 64 rows x 256 cols, 4 waves, each wave 64x64 (rf,cf in 0..3), BK=32
__launch_bounds__(256)
__global__ void gemm_kernel(const _Float16* __restrict__ Ah, const _Float16* __restrict__ Wt,
                            const float* __restrict__ xin, const float* __restrict__ bvec,
                            const float* __restrict__ gvec, const float* __restrict__ bevec,
                            float* __restrict__ xout) {
    __shared__ _Float16 sA[2][64 * 32];
    __shared__ _Float16 sB[2][256 * 32];
    __shared__ float st_s[64][4];
    __shared__ float st_q[64][4];

    const int tid  = threadIdx.x;
    const int lane = tid & 63;
    const int w    = tid >> 6;
    const int i0   = blockIdx.x * 64;

    // LDS read offsets (halves), XOR chunk swizzle: chunk' = chunk ^ ((row>>1)&3)
    int a_off[4], b_off[4];
    #pragma unroll
    for (int rf = 0; rf < 4; rf++) {
        int r = rf * 16 + (lane & 15);
        a_off[rf] = r * 32 + ((((lane >> 4) ^ ((r >> 1) & 3)) & 3) << 3);
    }
    #pragma unroll
    for (int cf = 0; cf < 4; cf++) {
        int n = w * 64 + cf * 16 + (lane & 15);
        b_off[cf] = n * 32 + ((((lane >> 4) ^ ((n >> 1) & 3)) & 3) << 3);
    }

    // staging sources (pre-swizzled global address, linear LDS dest)
    int arow = w * 16 + (lane >> 2);
    int acol = (((lane & 3) ^ ((arow >> 1) & 3)) & 3) << 3;   // halves
    const char* a_src = (const char*)(Ah + (size_t)(i0 + arow) * K13 + acol);
    const char* b_src[4];
    #pragma unroll
    for (int q = 0; q < 4; q++) {
        int n = q * 64 + w * 16 + (lane >> 2);
        int c = (((lane & 3) ^ ((n >> 1) & 3)) & 3) << 3;
        b_src[q] = (const char*)(Wt + (size_t)n * K13 + c);
    }

    floatx4 acc[4][4];
    #pragma unroll
    for (int rf = 0; rf < 4; rf++)
        #pragma unroll
        for (int cf = 0; cf < 4; cf++)
            acc[rf][cf] = (floatx4){0.f, 0.f, 0.f, 0.f};

    const int NSTEP = K13 / 32;   // 104
    // prologue: stage step 0 into buf 0
    gload16(a_src, (char*)(&sA[0][0]) + w * 1024);
    #pragma unroll
    for (int q = 0; q < 4; q++)
        gload16(b_src[q], (char*)(&sB[0][0]) + (q * 256 + w * 64) * 16);

    int cur = 0;
    for (int step = 0; step < NSTEP; step++) {
        __syncthreads();   // staged tile ready (vmcnt drained); prev reads done (lgkmcnt)
        if (step + 1 < NSTEP) {
            size_t koff = (size_t)(step + 1) * 64;  // 32 halves * 2B
            gload16(a_src + koff, (char*)(&sA[cur ^ 1][0]) + w * 1024);
            #pragma unroll
            for (int q = 0; q < 4; q++)
                gload16(b_src[q] + koff, (char*)(&sB[cur ^ 1][0]) + (q * 256 + w * 64) * 16);
        }
        half8 af[4], bf[4];
        #pragma unroll
        for (int rf = 0; rf < 4; rf++) af[rf] = *(const half8*)(&sA[cur][a_off[rf]]);
        #pragma unroll
        for (int cf = 0; cf < 4; cf++) bf[cf] = *(const half8*)(&sB[cur][b_off[cf]]);
        #pragma unroll
        for (int rf = 0; rf < 4; rf++)
            #pragma unroll
            for (int cf = 0; cf < 4; cf++)
                acc[rf][cf] = __builtin_amdgcn_mfma_f32_16x16x32_f16(af[rf], bf[cf], acc[rf][cf], 0, 0, 0);
        cur ^= 1;
    }

    // ---- epilogue: bias, LN stats (row over 256 cols), relu, residual ----
    float bcol[4], gcol[4], ecol[4];
    #pragma unroll
    for (int cf = 0; cf < 4; cf++) {
        int col = w * 64 + cf * 16 + (lane & 15);
        bcol[cf] = bvec[col]; gcol[cf] = gvec[col]; ecol[cf] = bevec[col];
    }
    #pragma unroll
    for (int rf = 0; rf < 4; rf++)
        #pragma unroll
        for (int cf = 0; cf < 4; cf++)
            #pragma unroll
            for (int j = 0; j < 4; j++)
                acc[rf][cf][j] += bcol[cf];

    float ssum[4][4], ssq[4][4];
    #pragma unroll
    for (int rf = 0; rf < 4; rf++)
        #pragma unroll
        for (int j = 0; j < 4; j++) {
            float s = acc[rf][0][j] + acc[rf][1][j] + acc[rf][2][j] + acc[rf][3][j];
            float q = acc[rf][0][j]*acc[rf][0][j] + acc[rf][1][j]*acc[rf][1][j]
                    + acc[rf][2][j]*acc[rf][2][j] + acc[rf][3][j]*acc[rf][3][j];
            #pragma unroll
            for (int off = 1; off < 16; off <<= 1) {
                s += __shfl_xor(s, off);
                q += __shfl_xor(q, off);
            }
            ssum[rf][j] = s; ssq[rf][j] = q;
        }
    if ((lane & 15) == 0) {
        #pragma unroll
        for (int rf = 0; rf < 4; rf++)
            #pragma unroll
            for (int j = 0; j < 4; j++) {
                int rl = rf * 16 + (lane >> 4) * 4 + j;
                st_s[rl][w] = ssum[rf][j];
                st_q[rl][w] = ssq[rf][j];
            }
    }
    __syncthreads();

    #pragma unroll
    for (int rf = 0; rf < 4; rf++)
        #pragma unroll
        for (int j = 0; j < 4; j++) {
            int rl = rf * 16 + (lane >> 4) * 4 + j;
            int grow = i0 + rl;
            float S = st_s[rl][0] + st_s[rl][1] + st_s[rl][2] + st_s[rl][3];
            float Q = st_q[rl][0] + st_q[rl][1] + st_q[rl][2] + st_q[rl][3];
            float mu  = S * (1.0f / 256.0f);
            float var = Q * (1.0f / 256.0f) - mu * mu;
            float rs  = rsqrtf(var + EPS_LN);
            if (grow < N_NODES) {
                const float* xr = xin + (size_t)grow * 256;
                float* orow = xout + (size_t)grow * 256;
                #pragma unroll
                for (int cf = 0; cf < 4; cf++) {
                    int col = w * 64 + cf * 16 + (lane & 15);
                    float h = acc[rf][cf][j];
                    orow[col] = fmaxf((h - mu) * rs * gcol[cf] + ecol[cf], 0.f) + xr[col];
                }
            }
        }
}

// ---------------- final scoring ----------------
__global__ void score_kernel(const float* __restrict__ x, const float* __restrict__ remb,
                             const int* __restrict__ batch, float* __restrict__ out) {
    int wid = threadIdx.x >> 6, lane = threadIdx.x & 63;
    int g = blockIdx.x * 4 + wid;
    if (g >= B_BATCH * K_BATCH) return;
    int si = batch[g * 3 + 0], ri = batch[g * 3 + 1], ti = batch[g * 3 + 2];
    const float4* xs = (const float4*)(x + (size_t)si * 256);
    const float4* xr = (const float4*)(remb + (size_t)ri * 256);
    const float4* xt = (const float4*)(x + (size_t)ti * 256);
    float4 a = xs[lane], r = xr[lane], t = xt[lane];
    float p = a.x*r.x*t.x + a.y*r.y*t.y + a.z*r.z*t.z + a.w*r.w*t.w;
    #pragma unroll
    for (int off = 1; off < 64; off <<= 1) p += __shfl_xor(p, off);
    if (lane == 0) out[g] = p;
}

extern "C" void kernel_launch(void* const* d_in, const int* in_sizes, int n_in,
                              void* d_out, int out_size, void* d_ws, size_t ws_size,
                              hipStream_t stream) {
    const float* x_in     = (const float*)d_in[0];
    const float* rel_embs = (const float*)d_in[1];
    const float* Ws       = (const float*)d_in[2];
    const float* bs       = (const float*)d_in[3];
    const float* ln_s     = (const float*)d_in[4];
    const float* ln_b     = (const float*)d_in[5];
    const float* remb     = (const float*)d_in[6];
    const int*   eidx     = (const int*)d_in[7];
    const int*   etype    = (const int*)d_in[8];
    const int*   batch    = (const int*)d_in[9];
    float* out = (float*)d_out;

    char* wp = (char*)d_ws;
    size_t o = 0;
    auto alloc = [&](size_t bytes) { void* p = wp + o; o += (bytes + 255) & ~255ull; return p; };
    int*      deg_in  = (int*)     alloc((size_t)N_NODES * 4);
    int*      offs    = (int*)     alloc((size_t)N_NODES * 4);
    int*      cursor  = (int*)     alloc((size_t)N_NODES * 4);
    float*    s1      = (float*)   alloc((size_t)N_NODES * 4);
    float*    s2      = (float*)   alloc((size_t)N_NODES * 4);
    float*    sum_log = (float*)   alloc(256);
    int*      csr_src = (int*)     alloc((size_t)E_EDGES * 4);
    int*      csr_et  = (int*)     alloc((size_t)E_EDGES * 4);
    _Float16* Ah      = (_Float16*)alloc((size_t)M_PAD * K13 * 2);       // 66.9 MB
    _Float16* Wt      = (_Float16*)alloc((size_t)L_LAYERS * 256 * K13 * 2); // 10.2 MB
    float*    xb0     = (float*)   alloc((size_t)M_PAD * 256 * 4);       // 10.3 MB
    float*    xb1     = (float*)   alloc((size_t)M_PAD * 256 * 4);       // total ~99 MB

    const int* src  = eidx;
    const int* dstp = eidx + E_EDGES;

    hipMemsetAsync(deg_in, 0, (size_t)N_NODES * 4, stream);
    hist_kernel<<<(E_EDGES + 255) / 256, 256, 0, stream>>>(dstp, deg_in);
    scan_kernel<<<1, 1024, 0, stream>>>(deg_in, offs, cursor, sum_log);
    fill_kernel<<<(E_EDGES + 255) / 256, 256, 0, stream>>>(src, dstp, etype, cursor, csr_src, csr_et);
    scales_kernel<<<(N_NODES + 255) / 256, 256, 0, stream>>>(deg_in, sum_log, s1, s2);
    {
        const int TOT = L_LAYERS * 256 * K13;
        wt_kernel<<<(TOT + 255) / 256, 256, 0, stream>>>(Ws, Wt);
    }
    hipMemcpyAsync(xb0, x_in, (size_t)N_NODES * 256 * 4, hipMemcpyDeviceToDevice, stream);

    float* xc = xb0; float* xn = xb1;
    for (int l = 0; l < L_LAYERS; l++) {
        agg_kernel<<<(N_NODES + 3) / 4, 256, 0, stream>>>(
            xc, rel_embs + (size_t)l * R_REL * 256, offs, deg_in, csr_src, csr_et, s1, s2, Ah);
        gemm_kernel<<<M_PAD / 64, 256, 0, stream>>>(
            Ah, Wt + (size_t)l * 256 * K13, xc,
            bs + (size_t)l * 256, ln_s + (size_t)l * 256, ln_b + (size_t)l * 256, xn);
        float* t = xc; xc = xn; xn = t;
    }
    score_kernel<<<(B_BATCH * K_BATCH + 3) / 4, 256, 0, stream>>>(xc, remb, batch, out);
}

// Round 3
// 805.292 us; speedup vs baseline: 6.7361x; 1.0824x over previous
//
#include <hip/hip_runtime.h>
#include <math.h>

typedef __attribute__((ext_vector_type(8))) _Float16 half8;
typedef __attribute__((ext_vector_type(4))) _Float16 half4;
typedef __attribute__((ext_vector_type(4))) float    floatx4;

#define N_NODES 10000
#define M_PAD   10048      // 157 * 64
#define E_EDGES 160000
#define DIM     256
#define R_REL   237
#define L_LAYERS 6
#define B_BATCH 128
#define K_BATCH 33
#define K13     3328       // 13*256
#define NSTEP   104        // K13/32
#define EPS_STD 1e-6f
#define EPS_LN  1e-5f

// ---------------- CSR build ----------------
__global__ void hist_kernel(const int* __restrict__ dst, int* __restrict__ deg) {
    int e = blockIdx.x * blockDim.x + threadIdx.x;
    if (e < E_EDGES) atomicAdd(&deg[dst[e]], 1);
}

__global__ void scan_kernel(const int* __restrict__ deg_in, int* __restrict__ offs,
                            int* __restrict__ cursor, float* __restrict__ sum_log) {
    __shared__ int   part[1024];
    __shared__ float slog[1024];
    int t = threadIdx.x;
    const int CH = 10;
    int base = t * CH;
    int lsum = 0; float ls = 0.f;
    for (int j = 0; j < CH; j++) {
        int i = base + j;
        if (i < N_NODES) { int d = deg_in[i]; lsum += d; ls += logf((float)(d + 1)); }
    }
    part[t] = lsum; slog[t] = ls;
    __syncthreads();
    for (int off = 1; off < 1024; off <<= 1) {
        int v = (t >= off) ? part[t - off] : 0;
        __syncthreads();
        part[t] += v;
        __syncthreads();
    }
    int run = part[t] - lsum;
    for (int j = 0; j < CH; j++) {
        int i = base + j;
        if (i < N_NODES) { offs[i] = run; cursor[i] = run; run += deg_in[i]; }
    }
    __syncthreads();
    for (int off = 512; off > 0; off >>= 1) {
        if (t < off) slog[t] += slog[t + off];
        __syncthreads();
    }
    if (t == 0) sum_log[0] = slog[0];
}

__global__ void fill_kernel(const int* __restrict__ src, const int* __restrict__ dst,
                            const int* __restrict__ et, int* __restrict__ cursor,
                            int* __restrict__ csr_src, int* __restrict__ csr_et) {
    int e = blockIdx.x * blockDim.x + threadIdx.x;
    if (e < E_EDGES) {
        int d = dst[e];
        int p = atomicAdd(&cursor[d], 1);
        csr_src[p] = src[e];
        csr_et[p]  = et[e];
    }
}

__global__ void scales_kernel(const int* __restrict__ deg_in, const float* __restrict__ sum_log,
                              float* __restrict__ s1, float* __restrict__ s2) {
    int i = blockIdx.x * blockDim.x + threadIdx.x;
    if (i < N_NODES) {
        float mean = sum_log[0] * (1.0f / (float)N_NODES);
        float sc = logf((float)(deg_in[i] + 1)) / mean;
        s1[i] = sc;
        s2[i] = 1.0f / fmaxf(sc, 0.01f);
    }
}

// -------- W transpose + fp16 pack: Wt[l][n][k] = W[l][k][n] --------
__global__ void wt_kernel(const float* __restrict__ Ws, _Float16* __restrict__ Wt) {
    int idx = blockIdx.x * 256 + threadIdx.x;
    const int TOT = L_LAYERS * 256 * K13;
    if (idx >= TOT) return;
    int l = idx / (256 * K13);
    int r = idx - l * (256 * K13);
    int n = r / K13, k = r - n * K13;
    Wt[idx] = (_Float16)Ws[(size_t)l * K13 * 256 + (size_t)k * 256 + n];
}

// ---- aggregation: one wave per node; emits fp16 A row (scale-folded, k-interleaved) ----
__global__ void agg_kernel(const float* __restrict__ x, const float* __restrict__ rel,
                           const int* __restrict__ offs, const int* __restrict__ deg_in,
                           const int* __restrict__ csr_src, const int* __restrict__ csr_et,
                           const float* __restrict__ s1a, const float* __restrict__ s2a,
                           _Float16* __restrict__ Ah) {
    int wid  = threadIdx.x >> 6;
    int lane = threadIdx.x & 63;
    int node = blockIdx.x * 4 + wid;
    if (node >= N_NODES) return;
    int off = offs[node];
    int dc  = deg_in[node];
    const float4* xv4 = (const float4*)x;
    const float4* rv4 = (const float4*)rel;
    float sx=0,sy=0,sz=0,sw=0, qx=0,qy=0,qz=0,qw=0;
    float mxx=-INFINITY,mxy=-INFINITY,mxz=-INFINITY,mxw=-INFINITY;
    float mnx= INFINITY,mny= INFINITY,mnz= INFINITY,mnw= INFINITY;
    for (int idx = off; idx < off + dc; idx++) {
        int s  = csr_src[idx];
        int et = csr_et[idx];
        float4 xv = xv4[(size_t)s * 64 + lane];
        float4 rv = rv4[(size_t)et * 64 + lane];
        float mx_ = xv.x * rv.x, my_ = xv.y * rv.y, mz_ = xv.z * rv.z, mw_ = xv.w * rv.w;
        sx += mx_; sy += my_; sz += mz_; sw += mw_;
        qx += mx_*mx_; qy += my_*my_; qz += mz_*mz_; qw += mw_*mw_;
        mxx = fmaxf(mxx, mx_); mxy = fmaxf(mxy, my_); mxz = fmaxf(mxz, mz_); mxw = fmaxf(mxw, mw_);
        mnx = fminf(mnx, mx_); mny = fminf(mny, my_); mnz = fminf(mnz, mz_); mnw = fminf(mnw, mw_);
    }
    float4 xself = xv4[(size_t)node * 64 + lane];
    sx += xself.x; sy += xself.y; sz += xself.z; sw += xself.w;
    qx += xself.x*xself.x; qy += xself.y*xself.y; qz += xself.z*xself.z; qw += xself.w*xself.w;
    mxx = fmaxf(mxx, xself.x); mxy = fmaxf(mxy, xself.y); mxz = fmaxf(mxz, xself.z); mxw = fmaxf(mxw, xself.w);
    mnx = fminf(mnx, xself.x); mny = fminf(mny, xself.y); mnz = fminf(mnz, xself.z); mnw = fminf(mnw, xself.w);

    float inv = 1.0f / (float)(dc + 1);
    float4 mean = {sx*inv, sy*inv, sz*inv, sw*inv};
    float4 mx = {mxx,mxy,mxz,mxw};
    float4 mn = {mnx,mny,mnz,mnw};
    float4 sd = {
        sqrtf(fmaxf(qx*inv - mean.x*mean.x, EPS_STD)),
        sqrtf(fmaxf(qy*inv - mean.y*mean.y, EPS_STD)),
        sqrtf(fmaxf(qz*inv - mean.z*mean.z, EPS_STD)),
        sqrtf(fmaxf(qw*inv - mean.w*mean.w, EPS_STD))};

    float s1v = s1a[node], s2v = s2a[node];
    half4* outp = (half4*)(Ah + (size_t)node * K13);
    // A col layout: k = (t*256+d)*3 + s  (t=feat type, d=dim, s=scale idx), then x at 3072+
    #pragma unroll
    for (int t = 0; t < 4; t++) {
        float4 v = (t == 0) ? mean : (t == 1 ? mx : (t == 2 ? mn : sd));
        int base = t * 192 + 3 * lane;
        half4 h0 = { (_Float16)v.x, (_Float16)(v.x*s1v), (_Float16)(v.x*s2v), (_Float16)v.y };
        half4 h1 = { (_Float16)(v.y*s1v), (_Float16)(v.y*s2v), (_Float16)v.z, (_Float16)(v.z*s1v) };
        half4 h2 = { (_Float16)(v.z*s2v), (_Float16)v.w, (_Float16)(v.w*s1v), (_Float16)(v.w*s2v) };
        outp[base] = h0; outp[base+1] = h1; outp[base+2] = h2;
    }
    half4 hx = { (_Float16)xself.x, (_Float16)xself.y, (_Float16)xself.z, (_Float16)xself.w };
    outp[768 + lane] = hx;
}

// ---------------- fp16 MFMA GEMM: single-wave 64x64 tiles, no LDS, no barriers ----
// grid = (M_PAD/64) * (256/64) = 157*4 = 628 one-wave blocks
__launch_bounds__(64, 2)
__global__ void gemm_kernel(const _Float16* __restrict__ Ah, const _Float16* __restrict__ Wt,
                            float* __restrict__ hbuf) {
    // bijective XCD swizzle (nwg=628): co-locate the 4 n-blocks of an m-strip per XCD
    const int NW = 628, NX = 8, q = NW / NX, r = NW % NX;
    int orig = blockIdx.x;
    int xcd = orig % NX, loc = orig / NX;
    int wg = (xcd < r ? xcd * (q + 1) : r * (q + 1) + (xcd - r) * q) + loc;
    int m0 = (wg >> 2) * 64;
    int n0 = (wg & 3) * 64;

    int lane  = threadIdx.x;
    int row_l = lane & 15;
    int kq    = lane >> 4;        // 0..3, k-chunk of 8 halves

    const _Float16* aBase = Ah + (size_t)(m0 + row_l) * K13 + kq * 8;
    const _Float16* bBase = Wt + (size_t)(n0 + row_l) * K13 + kq * 8;

    floatx4 acc[4][4];
    #pragma unroll
    for (int rf = 0; rf < 4; rf++)
        #pragma unroll
        for (int cf = 0; cf < 4; cf++)
            acc[rf][cf] = (floatx4){0.f, 0.f, 0.f, 0.f};

    half8 a0[4], b0[4], a1[4], b1[4], a2[4], b2[4], a3[4], b3[4];

#define LOADSTEP(AF, BF, S) do { \
    const _Float16* ak_ = aBase + (S) * 32; \
    const _Float16* bk_ = bBase + (S) * 32; \
    AF[0] = *(const half8*)(ak_); \
    AF[1] = *(const half8*)(ak_ + 16 * K13); \
    AF[2] = *(const half8*)(ak_ + 32 * K13); \
    AF[3] = *(const half8*)(ak_ + 48 * K13); \
    BF[0] = *(const half8*)(bk_); \
    BF[1] = *(const half8*)(bk_ + 16 * K13); \
    BF[2] = *(const half8*)(bk_ + 32 * K13); \
    BF[3] = *(const half8*)(bk_ + 48 * K13); \
} while (0)

#define DOMFMA(AF, BF) do { \
    _Pragma("unroll") \
    for (int rf = 0; rf < 4; rf++) \
        _Pragma("unroll") \
        for (int cf = 0; cf < 4; cf++) \
            acc[rf][cf] = __builtin_amdgcn_mfma_f32_16x16x32_f16(AF[rf], BF[cf], acc[rf][cf], 0, 0, 0); \
} while (0)

    LOADSTEP(a0, b0, 0);
    LOADSTEP(a1, b1, 1);
    LOADSTEP(a2, b2, 2);
    for (int s = 0; s < NSTEP; s += 4) {
        if (s + 3 < NSTEP) LOADSTEP(a3, b3, s + 3);
        DOMFMA(a0, b0);
        if (s + 4 < NSTEP) LOADSTEP(a0, b0, s + 4);
        DOMFMA(a1, b1);
        if (s + 5 < NSTEP) LOADSTEP(a1, b1, s + 5);
        DOMFMA(a2, b2);
        if (s + 6 < NSTEP) LOADSTEP(a2, b2, s + 6);
        DOMFMA(a3, b3);
    }
#undef LOADSTEP
#undef DOMFMA

    // C/D layout: col = lane&15, row = (lane>>4)*4 + j  (verified mapping)
    #pragma unroll
    for (int rf = 0; rf < 4; rf++) {
        #pragma unroll
        for (int j = 0; j < 4; j++) {
            int grow = m0 + rf * 16 + kq * 4 + j;
            float* orow = hbuf + (size_t)grow * 256 + n0;
            #pragma unroll
            for (int cf = 0; cf < 4; cf++)
                orow[cf * 16 + row_l] = acc[rf][cf][j];
        }
    }
}

// ---------------- bias + LN + relu + residual ----------------
__global__ void ln_kernel(const float* __restrict__ hbuf, const float* __restrict__ xin,
                          const float* __restrict__ bvec, const float* __restrict__ gvec,
                          const float* __restrict__ evec, float* __restrict__ xout) {
    int wid = threadIdx.x >> 6, lane = threadIdx.x & 63;
    int row = blockIdx.x * 4 + wid;
    if (row >= N_NODES) return;
    float4 hv = ((const float4*)(hbuf + (size_t)row * 256))[lane];
    float4 bv = ((const float4*)bvec)[lane];
    hv.x += bv.x; hv.y += bv.y; hv.z += bv.z; hv.w += bv.w;
    float s = hv.x + hv.y + hv.z + hv.w;
    float qsq = hv.x*hv.x + hv.y*hv.y + hv.z*hv.z + hv.w*hv.w;
    #pragma unroll
    for (int off = 1; off < 64; off <<= 1) {
        s   += __shfl_xor(s, off);
        qsq += __shfl_xor(qsq, off);
    }
    float mu  = s * (1.0f / 256.0f);
    float var = qsq * (1.0f / 256.0f) - mu * mu;
    float rs  = rsqrtf(var + EPS_LN);
    float4 g = ((const float4*)gvec)[lane];
    float4 e = ((const float4*)evec)[lane];
    float4 xv = ((const float4*)(xin + (size_t)row * 256))[lane];
    float4 o;
    o.x = fmaxf((hv.x - mu) * rs * g.x + e.x, 0.f) + xv.x;
    o.y = fmaxf((hv.y - mu) * rs * g.y + e.y, 0.f) + xv.y;
    o.z = fmaxf((hv.z - mu) * rs * g.z + e.z, 0.f) + xv.z;
    o.w = fmaxf((hv.w - mu) * rs * g.w + e.w, 0.f) + xv.w;
    ((float4*)(xout + (size_t)row * 256))[lane] = o;
}

// ---------------- final scoring ----------------
__global__ void score_kernel(const float* __restrict__ x, const float* __restrict__ remb,
                             const int* __restrict__ batch, float* __restrict__ out) {
    int wid = threadIdx.x >> 6, lane = threadIdx.x & 63;
    int g = blockIdx.x * 4 + wid;
    if (g >= B_BATCH * K_BATCH) return;
    int si = batch[g * 3 + 0], ri = batch[g * 3 + 1], ti = batch[g * 3 + 2];
    const float4* xs = (const float4*)(x + (size_t)si * 256);
    const float4* xr = (const float4*)(remb + (size_t)ri * 256);
    const float4* xt = (const float4*)(x + (size_t)ti * 256);
    float4 a = xs[lane], r = xr[lane], t = xt[lane];
    float p = a.x*r.x*t.x + a.y*r.y*t.y + a.z*r.z*t.z + a.w*r.w*t.w;
    #pragma unroll
    for (int off = 1; off < 64; off <<= 1) p += __shfl_xor(p, off);
    if (lane == 0) out[g] = p;
}

extern "C" void kernel_launch(void* const* d_in, const int* in_sizes, int n_in,
                              void* d_out, int out_size, void* d_ws, size_t ws_size,
                              hipStream_t stream) {
    const float* x_in     = (const float*)d_in[0];
    const float* rel_embs = (const float*)d_in[1];
    const float* Ws       = (const float*)d_in[2];
    const float* bs       = (const float*)d_in[3];
    const float* ln_s     = (const float*)d_in[4];
    const float* ln_b     = (const float*)d_in[5];
    const float* remb     = (const float*)d_in[6];
    const int*   eidx     = (const int*)d_in[7];
    const int*   etype    = (const int*)d_in[8];
    const int*   batch    = (const int*)d_in[9];
    float* out = (float*)d_out;

    char* wp = (char*)d_ws;
    size_t o = 0;
    auto alloc = [&](size_t bytes) { void* p = wp + o; o += (bytes + 255) & ~255ull; return p; };
    int*      deg_in  = (int*)     alloc((size_t)N_NODES * 4);
    int*      offs    = (int*)     alloc((size_t)N_NODES * 4);
    int*      cursor  = (int*)     alloc((size_t)N_NODES * 4);
    float*    s1      = (float*)   alloc((size_t)N_NODES * 4);
    float*    s2      = (float*)   alloc((size_t)N_NODES * 4);
    float*    sum_log = (float*)   alloc(256);
    int*      csr_src = (int*)     alloc((size_t)E_EDGES * 4);
    int*      csr_et  = (int*)     alloc((size_t)E_EDGES * 4);
    _Float16* Ah      = (_Float16*)alloc((size_t)M_PAD * K13 * 2);          // 66.9 MB
    _Float16* Wt      = (_Float16*)alloc((size_t)L_LAYERS * 256 * K13 * 2); // 10.2 MB
    float*    hbuf    = (float*)   alloc((size_t)M_PAD * 256 * 4);          // 10.3 MB
    float*    xb0     = (float*)   alloc((size_t)M_PAD * 256 * 4);
    float*    xb1     = (float*)   alloc((size_t)M_PAD * 256 * 4);

    const int* src  = eidx;
    const int* dstp = eidx + E_EDGES;

    hipMemsetAsync(deg_in, 0, (size_t)N_NODES * 4, stream);
    hist_kernel<<<(E_EDGES + 255) / 256, 256, 0, stream>>>(dstp, deg_in);
    scan_kernel<<<1, 1024, 0, stream>>>(deg_in, offs, cursor, sum_log);
    fill_kernel<<<(E_EDGES + 255) / 256, 256, 0, stream>>>(src, dstp, etype, cursor, csr_src, csr_et);
    scales_kernel<<<(N_NODES + 255) / 256, 256, 0, stream>>>(deg_in, sum_log, s1, s2);
    {
        const int TOT = L_LAYERS * 256 * K13;
        wt_kernel<<<(TOT + 255) / 256, 256, 0, stream>>>(Ws, Wt);
    }
    hipMemcpyAsync(xb0, x_in, (size_t)N_NODES * 256 * 4, hipMemcpyDeviceToDevice, stream);

    float* xc = xb0; float* xn = xb1;
    for (int l = 0; l < L_LAYERS; l++) {
        agg_kernel<<<(N_NODES + 3) / 4, 256, 0, stream>>>(
            xc, rel_embs + (size_t)l * R_REL * 256, offs, deg_in, csr_src, csr_et, s1, s2, Ah);
        gemm_kernel<<<628, 64, 0, stream>>>(Ah, Wt + (size_t)l * 256 * K13, hbuf);
        ln_kernel<<<(N_NODES + 3) / 4, 256, 0, stream>>>(
            hbuf, xc, bs + (size_t)l * 256, ln_s + (size_t)l * 256, ln_b + (size_t)l * 256, xn);
        float* t = xc; xc = xn; xn = t;
    }
    score_kernel<<<(B_BATCH * K_BATCH + 3) / 4, 256, 0, stream>>>(xc, remb, batch, out);
}

// Round 5
// 785.393 us; speedup vs baseline: 6.9067x; 1.0253x over previous
//
#include <hip/hip_runtime.h>
#include <math.h>

typedef __attribute__((ext_vector_type(8))) _Float16 half8;
typedef __attribute__((ext_vector_type(4))) _Float16 half4;
typedef __attribute__((ext_vector_type(4))) float    floatx4;

#define N_NODES 10000
#define M_PAD   10048      // 157 * 64
#define E_EDGES 160000
#define DIM     256
#define R_REL   237
#define L_LAYERS 6
#define B_BATCH 128
#define K_BATCH 33
#define K13     3328       // 13*256
#define KSPLIT  4
#define KSLICE  832        // K13/KSPLIT (halves)
#define KS_STEPS 26        // KSLICE/32  (26 = 24 pipelined + 2 tail)
#define EPS_STD 1e-6f
#define EPS_LN  1e-5f

// ---------------- CSR build ----------------
__global__ void hist_kernel(const int* __restrict__ dst, int* __restrict__ deg) {
    int e = blockIdx.x * blockDim.x + threadIdx.x;
    if (e < E_EDGES) atomicAdd(&deg[dst[e]], 1);
}

__global__ void scan_kernel(const int* __restrict__ deg_in, int* __restrict__ offs,
                            int* __restrict__ cursor, float* __restrict__ sum_log) {
    __shared__ int   part[1024];
    __shared__ float slog[1024];
    int t = threadIdx.x;
    const int CH = 10;
    int base = t * CH;
    int lsum = 0; float ls = 0.f;
    for (int j = 0; j < CH; j++) {
        int i = base + j;
        if (i < N_NODES) { int d = deg_in[i]; lsum += d; ls += logf((float)(d + 1)); }
    }
    part[t] = lsum; slog[t] = ls;
    __syncthreads();
    for (int off = 1; off < 1024; off <<= 1) {
        int v = (t >= off) ? part[t - off] : 0;
        __syncthreads();
        part[t] += v;
        __syncthreads();
    }
    int run = part[t] - lsum;
    for (int j = 0; j < CH; j++) {
        int i = base + j;
        if (i < N_NODES) { offs[i] = run; cursor[i] = run; run += deg_in[i]; }
    }
    __syncthreads();
    for (int off = 512; off > 0; off >>= 1) {
        if (t < off) slog[t] += slog[t + off];
        __syncthreads();
    }
    if (t == 0) sum_log[0] = slog[0];
}

__global__ void fill_kernel(const int* __restrict__ src, const int* __restrict__ dst,
                            const int* __restrict__ et, int* __restrict__ cursor,
                            int* __restrict__ csr_src, int* __restrict__ csr_et) {
    int e = blockIdx.x * blockDim.x + threadIdx.x;
    if (e < E_EDGES) {
        int d = dst[e];
        int p = atomicAdd(&cursor[d], 1);
        csr_src[p] = src[e];
        csr_et[p]  = et[e];
    }
}

__global__ void scales_kernel(const int* __restrict__ deg_in, const float* __restrict__ sum_log,
                              float* __restrict__ s1, float* __restrict__ s2) {
    int i = blockIdx.x * blockDim.x + threadIdx.x;
    if (i < N_NODES) {
        float mean = sum_log[0] * (1.0f / (float)N_NODES);
        float sc = logf((float)(deg_in[i] + 1)) / mean;
        s1[i] = sc;
        s2[i] = 1.0f / fmaxf(sc, 0.01f);
    }
}

// -------- W transpose + fp16 pack: Wt[l][n][k] = W[l][k][n] --------
__global__ void wt_kernel(const float* __restrict__ Ws, _Float16* __restrict__ Wt) {
    int idx = blockIdx.x * 256 + threadIdx.x;
    const int TOT = L_LAYERS * 256 * K13;
    if (idx >= TOT) return;
    int l = idx / (256 * K13);
    int r = idx - l * (256 * K13);
    int n = r / K13, k = r - n * K13;
    Wt[idx] = (_Float16)Ws[(size_t)l * K13 * 256 + (size_t)k * 256 + n];
}

// -------- fp32 -> fp16 converter --------
__global__ void cvt_kernel(const float* __restrict__ in, _Float16* __restrict__ outp, int n) {
    int i = blockIdx.x * 256 + threadIdx.x;
    if (i < n) outp[i] = (_Float16)in[i];
}

// ---- aggregation: one wave per node; fp16 gather, fp32 stats; emits fp16 A row ----
__global__ void agg_kernel(const float* __restrict__ x, const _Float16* __restrict__ xh,
                           const _Float16* __restrict__ relh,
                           const int* __restrict__ offs, const int* __restrict__ deg_in,
                           const int* __restrict__ csr_src, const int* __restrict__ csr_et,
                           const float* __restrict__ s1a, const float* __restrict__ s2a,
                           _Float16* __restrict__ Ah) {
    int wid  = threadIdx.x >> 6;
    int lane = threadIdx.x & 63;
    int node = blockIdx.x * 4 + wid;
    if (node >= N_NODES) return;
    int off = offs[node];
    int dc  = deg_in[node];
    const half4* xh4 = (const half4*)xh;
    const half4* rh4 = (const half4*)relh;
    float sx=0,sy=0,sz=0,sw=0, qx=0,qy=0,qz=0,qw=0;
    float mxx=-INFINITY,mxy=-INFINITY,mxz=-INFINITY,mxw=-INFINITY;
    float mnx= INFINITY,mny= INFINITY,mnz= INFINITY,mnw= INFINITY;
    for (int idx = off; idx < off + dc; idx++) {
        int s  = csr_src[idx];
        int et = csr_et[idx];
        half4 xv = xh4[(size_t)s * 64 + lane];
        half4 rv = rh4[(size_t)et * 64 + lane];
        float mx_ = (float)xv.x * (float)rv.x;
        float my_ = (float)xv.y * (float)rv.y;
        float mz_ = (float)xv.z * (float)rv.z;
        float mw_ = (float)xv.w * (float)rv.w;
        sx += mx_; sy += my_; sz += mz_; sw += mw_;
        qx += mx_*mx_; qy += my_*my_; qz += mz_*mz_; qw += mw_*mw_;
        mxx = fmaxf(mxx, mx_); mxy = fmaxf(mxy, my_); mxz = fmaxf(mxz, mz_); mxw = fmaxf(mxw, mw_);
        mnx = fminf(mnx, mx_); mny = fminf(mny, my_); mnz = fminf(mnz, mz_); mnw = fminf(mnw, mw_);
    }
    // self loop message = x (fp32, exact)
    float4 xself = ((const float4*)x)[(size_t)node * 64 + lane];
    sx += xself.x; sy += xself.y; sz += xself.z; sw += xself.w;
    qx += xself.x*xself.x; qy += xself.y*xself.y; qz += xself.z*xself.z; qw += xself.w*xself.w;
    mxx = fmaxf(mxx, xself.x); mxy = fmaxf(mxy, xself.y); mxz = fmaxf(mxz, xself.z); mxw = fmaxf(mxw, xself.w);
    mnx = fminf(mnx, xself.x); mny = fminf(mny, xself.y); mnz = fminf(mnz, xself.z); mnw = fminf(mnw, xself.w);

    float inv = 1.0f / (float)(dc + 1);
    float4 mean = {sx*inv, sy*inv, sz*inv, sw*inv};
    float4 mx = {mxx,mxy,mxz,mxw};
    float4 mn = {mnx,mny,mnz,mnw};
    float4 sd = {
        sqrtf(fmaxf(qx*inv - mean.x*mean.x, EPS_STD)),
        sqrtf(fmaxf(qy*inv - mean.y*mean.y, EPS_STD)),
        sqrtf(fmaxf(qz*inv - mean.z*mean.z, EPS_STD)),
        sqrtf(fmaxf(qw*inv - mean.w*mean.w, EPS_STD))};

    float s1v = s1a[node], s2v = s2a[node];
    half4* outp = (half4*)(Ah + (size_t)node * K13);
    // A col layout: k = (t*256+d)*3 + s  (t=feat type, d=dim, s=scale idx), then x at 3072+
    #pragma unroll
    for (int t = 0; t < 4; t++) {
        float4 v = (t == 0) ? mean : (t == 1 ? mx : (t == 2 ? mn : sd));
        int base = t * 192 + 3 * lane;
        half4 h0 = { (_Float16)v.x, (_Float16)(v.x*s1v), (_Float16)(v.x*s2v), (_Float16)v.y };
        half4 h1 = { (_Float16)(v.y*s1v), (_Float16)(v.y*s2v), (_Float16)v.z, (_Float16)(v.z*s1v) };
        half4 h2 = { (_Float16)(v.z*s2v), (_Float16)v.w, (_Float16)(v.w*s1v), (_Float16)(v.w*s2v) };
        outp[base] = h0; outp[base+1] = h1; outp[base+2] = h2;
    }
    half4 hx = { (_Float16)xself.x, (_Float16)xself.y, (_Float16)xself.z, (_Float16)xself.w };
    outp[768 + lane] = hx;
}

// ---------------- fp16 MFMA GEMM: K-split x4, single-wave 64x64 tiles ----------------
// grid = 157 * 4 * KSPLIT = 2512 one-wave blocks; partial sums into hbuf[ks]
__launch_bounds__(64, 2)
__global__ void gemm_kernel(const _Float16* __restrict__ Ah, const _Float16* __restrict__ Wt,
                            float* __restrict__ hbuf) {
    const int NW = 628 * KSPLIT;                 // 2512, divisible by 8
    int orig = blockIdx.x;
    int wg = (orig & 7) * (NW >> 3) + (orig >> 3);   // XCD swizzle (bijective: NW%8==0)
    int ks  = wg / 628;
    int rem = wg - ks * 628;
    int m0 = (rem >> 2) * 64;
    int n0 = (rem & 3) * 64;
    int kbase = ks * KSLICE;

    int lane  = threadIdx.x;
    int row_l = lane & 15;
    int kq    = lane >> 4;        // 0..3, k-chunk of 8 halves

    const _Float16* aBase = Ah + (size_t)(m0 + row_l) * K13 + kbase + kq * 8;
    const _Float16* bBase = Wt + (size_t)(n0 + row_l) * K13 + kbase + kq * 8;

    floatx4 acc[4][4];
    #pragma unroll
    for (int rf = 0; rf < 4; rf++)
        #pragma unroll
        for (int cf = 0; cf < 4; cf++)
            acc[rf][cf] = (floatx4){0.f, 0.f, 0.f, 0.f};

    half8 a0[4], b0[4], a1[4], b1[4], a2[4], b2[4], a3[4], b3[4];

#define LOADSTEP(AF, BF, S) do { \
    const _Float16* ak_ = aBase + (S) * 32; \
    const _Float16* bk_ = bBase + (S) * 32; \
    AF[0] = *(const half8*)(ak_); \
    AF[1] = *(const half8*)(ak_ + 16 * K13); \
    AF[2] = *(const half8*)(ak_ + 32 * K13); \
    AF[3] = *(const half8*)(ak_ + 48 * K13); \
    BF[0] = *(const half8*)(bk_); \
    BF[1] = *(const half8*)(bk_ + 16 * K13); \
    BF[2] = *(const half8*)(bk_ + 32 * K13); \
    BF[3] = *(const half8*)(bk_ + 48 * K13); \
} while (0)

#define DOMFMA(AF, BF) do { \
    _Pragma("unroll") \
    for (int rf = 0; rf < 4; rf++) \
        _Pragma("unroll") \
        for (int cf = 0; cf < 4; cf++) \
            acc[rf][cf] = __builtin_amdgcn_mfma_f32_16x16x32_f16(AF[rf], BF[cf], acc[rf][cf], 0, 0, 0); \
} while (0)

    // 4-deep pipeline over the first 24 steps; steps 24,25 drain from a0,a1.
    LOADSTEP(a0, b0, 0);
    LOADSTEP(a1, b1, 1);
    LOADSTEP(a2, b2, 2);
    for (int s = 0; s < 24; s += 4) {
        LOADSTEP(a3, b3, s + 3);          // s+3 <= 23 < 26, always valid
        DOMFMA(a0, b0);
        LOADSTEP(a0, b0, s + 4);          // s+4 <= 24 < 26, always valid
        DOMFMA(a1, b1);
        LOADSTEP(a1, b1, s + 5);          // s+5 <= 25 < 26, always valid
        DOMFMA(a2, b2);
        if (s + 6 < KS_STEPS) LOADSTEP(a2, b2, s + 6);   // skipped at s=20
        DOMFMA(a3, b3);
    }
    DOMFMA(a0, b0);   // step 24
    DOMFMA(a1, b1);   // step 25
#undef LOADSTEP
#undef DOMFMA

    // C/D layout: col = lane&15, row = (lane>>4)*4 + j
    float* outb = hbuf + (size_t)ks * M_PAD * 256;
    #pragma unroll
    for (int rf = 0; rf < 4; rf++) {
        #pragma unroll
        for (int j = 0; j < 4; j++) {
            int grow = m0 + rf * 16 + kq * 4 + j;
            float* orow = outb + (size_t)grow * 256 + n0;
            #pragma unroll
            for (int cf = 0; cf < 4; cf++)
                orow[cf * 16 + row_l] = acc[rf][cf][j];
        }
    }
}

// ---------------- 4-way reduce + bias + LN + relu + residual (+fp16 mirror) ----------------
__global__ void ln_kernel(const float* __restrict__ hbuf, const float* __restrict__ xin,
                          const float* __restrict__ bvec, const float* __restrict__ gvec,
                          const float* __restrict__ evec, float* __restrict__ xout,
                          _Float16* __restrict__ xhout) {
    int wid = threadIdx.x >> 6, lane = threadIdx.x & 63;
    int row = blockIdx.x * 4 + wid;
    if (row >= N_NODES) return;
    const float4* p0 = (const float4*)(hbuf + (size_t)row * 256);
    const float4* p1 = (const float4*)(hbuf + (size_t)M_PAD * 256     + (size_t)row * 256);
    const float4* p2 = (const float4*)(hbuf + (size_t)M_PAD * 256 * 2 + (size_t)row * 256);
    const float4* p3 = (const float4*)(hbuf + (size_t)M_PAD * 256 * 3 + (size_t)row * 256);
    float4 h0 = p0[lane], h1 = p1[lane], h2 = p2[lane], h3 = p3[lane];
    float4 bv = ((const float4*)bvec)[lane];
    float4 hv;
    hv.x = h0.x + h1.x + h2.x + h3.x + bv.x;
    hv.y = h0.y + h1.y + h2.y + h3.y + bv.y;
    hv.z = h0.z + h1.z + h2.z + h3.z + bv.z;
    hv.w = h0.w + h1.w + h2.w + h3.w + bv.w;
    float s = hv.x + hv.y + hv.z + hv.w;
    float qsq = hv.x*hv.x + hv.y*hv.y + hv.z*hv.z + hv.w*hv.w;
    #pragma unroll
    for (int off = 1; off < 64; off <<= 1) {
        s   += __shfl_xor(s, off);
        qsq += __shfl_xor(qsq, off);
    }
    float mu  = s * (1.0f / 256.0f);
    float var = qsq * (1.0f / 256.0f) - mu * mu;
    float rs  = rsqrtf(var + EPS_LN);
    float4 g = ((const float4*)gvec)[lane];
    float4 e = ((const float4*)evec)[lane];
    float4 xv = ((const float4*)(xin + (size_t)row * 256))[lane];
    float4 o;
    o.x = fmaxf((hv.x - mu) * rs * g.x + e.x, 0.f) + xv.x;
    o.y = fmaxf((hv.y - mu) * rs * g.y + e.y, 0.f) + xv.y;
    o.z = fmaxf((hv.z - mu) * rs * g.z + e.z, 0.f) + xv.z;
    o.w = fmaxf((hv.w - mu) * rs * g.w + e.w, 0.f) + xv.w;
    ((float4*)(xout + (size_t)row * 256))[lane] = o;
    half4 oh = { (_Float16)o.x, (_Float16)o.y, (_Float16)o.z, (_Float16)o.w };
    ((half4*)(xhout + (size_t)row * 256))[lane] = oh;
}

// ---------------- final scoring ----------------
__global__ void score_kernel(const float* __restrict__ x, const float* __restrict__ remb,
                             const int* __restrict__ batch, float* __restrict__ out) {
    int wid = threadIdx.x >> 6, lane = threadIdx.x & 63;
    int g = blockIdx.x * 4 + wid;
    if (g >= B_BATCH * K_BATCH) return;
    int si = batch[g * 3 + 0], ri = batch[g * 3 + 1], ti = batch[g * 3 + 2];
    const float4* xs = (const float4*)(x + (size_t)si * 256);
    const float4* xr = (const float4*)(remb + (size_t)ri * 256);
    const float4* xt = (const float4*)(x + (size_t)ti * 256);
    float4 a = xs[lane], r = xr[lane], t = xt[lane];
    float p = a.x*r.x*t.x + a.y*r.y*t.y + a.z*r.z*t.z + a.w*r.w*t.w;
    #pragma unroll
    for (int off = 1; off < 64; off <<= 1) p += __shfl_xor(p, off);
    if (lane == 0) out[g] = p;
}

extern "C" void kernel_launch(void* const* d_in, const int* in_sizes, int n_in,
                              void* d_out, int out_size, void* d_ws, size_t ws_size,
                              hipStream_t stream) {
    const float* x_in     = (const float*)d_in[0];
    const float* rel_embs = (const float*)d_in[1];
    const float* Ws       = (const float*)d_in[2];
    const float* bs       = (const float*)d_in[3];
    const float* ln_s     = (const float*)d_in[4];
    const float* ln_b     = (const float*)d_in[5];
    const float* remb     = (const float*)d_in[6];
    const int*   eidx     = (const int*)d_in[7];
    const int*   etype    = (const int*)d_in[8];
    const int*   batch    = (const int*)d_in[9];
    float* out = (float*)d_out;

    char* wp = (char*)d_ws;
    size_t o = 0;
    auto alloc = [&](size_t bytes) { void* p = wp + o; o += (bytes + 255) & ~255ull; return p; };
    int*      deg_in  = (int*)     alloc((size_t)N_NODES * 4);
    int*      offs    = (int*)     alloc((size_t)N_NODES * 4);
    int*      cursor  = (int*)     alloc((size_t)N_NODES * 4);
    float*    s1      = (float*)   alloc((size_t)N_NODES * 4);
    float*    s2      = (float*)   alloc((size_t)N_NODES * 4);
    float*    sum_log = (float*)   alloc(256);
    int*      csr_src = (int*)     alloc((size_t)E_EDGES * 4);
    int*      csr_et  = (int*)     alloc((size_t)E_EDGES * 4);
    _Float16* Ah      = (_Float16*)alloc((size_t)M_PAD * K13 * 2);            // 66.9 MB
    _Float16* Wt      = (_Float16*)alloc((size_t)L_LAYERS * 256 * K13 * 2);   // 10.2 MB
    float*    hbuf    = (float*)   alloc((size_t)KSPLIT * M_PAD * 256 * 4);   // 41.2 MB
    float*    xb0     = (float*)   alloc((size_t)M_PAD * 256 * 4);
    float*    xb1     = (float*)   alloc((size_t)M_PAD * 256 * 4);
    _Float16* xh0     = (_Float16*)alloc((size_t)M_PAD * 256 * 2);
    _Float16* xh1     = (_Float16*)alloc((size_t)M_PAD * 256 * 2);
    _Float16* relh    = (_Float16*)alloc((size_t)L_LAYERS * R_REL * 256 * 2); // 0.73 MB

    const int* src  = eidx;
    const int* dstp = eidx + E_EDGES;

    hipMemsetAsync(deg_in, 0, (size_t)N_NODES * 4, stream);
    hist_kernel<<<(E_EDGES + 255) / 256, 256, 0, stream>>>(dstp, deg_in);
    scan_kernel<<<1, 1024, 0, stream>>>(deg_in, offs, cursor, sum_log);
    fill_kernel<<<(E_EDGES + 255) / 256, 256, 0, stream>>>(src, dstp, etype, cursor, csr_src, csr_et);
    scales_kernel<<<(N_NODES + 255) / 256, 256, 0, stream>>>(deg_in, sum_log, s1, s2);
    {
        const int TOT = L_LAYERS * 256 * K13;
        wt_kernel<<<(TOT + 255) / 256, 256, 0, stream>>>(Ws, Wt);
        const int RT = L_LAYERS * R_REL * 256;
        cvt_kernel<<<(RT + 255) / 256, 256, 0, stream>>>(rel_embs, relh, RT);
        const int XT = N_NODES * 256;
        cvt_kernel<<<(XT + 255) / 256, 256, 0, stream>>>(x_in, xh0, XT);
    }
    hipMemcpyAsync(xb0, x_in, (size_t)N_NODES * 256 * 4, hipMemcpyDeviceToDevice, stream);

    float* xc = xb0; float* xn = xb1;
    _Float16* xhc = xh0; _Float16* xhn = xh1;
    for (int l = 0; l < L_LAYERS; l++) {
        agg_kernel<<<(N_NODES + 3) / 4, 256, 0, stream>>>(
            xc, xhc, relh + (size_t)l * R_REL * 256,
            offs, deg_in, csr_src, csr_et, s1, s2, Ah);
        gemm_kernel<<<628 * KSPLIT, 64, 0, stream>>>(Ah, Wt + (size_t)l * 256 * K13, hbuf);
        ln_kernel<<<(N_NODES + 3) / 4, 256, 0, stream>>>(
            hbuf, xc, bs + (size_t)l * 256, ln_s + (size_t)l * 256, ln_b + (size_t)l * 256, xn, xhn);
        float* t = xc; xc = xn; xn = t;
        _Float16* th = xhc; xhc = xhn; xhn = th;
    }
    score_kernel<<<(B_BATCH * K_BATCH + 3) / 4, 256, 0, stream>>>(xc, remb, batch, out);
}

// Round 6
// 619.674 us; speedup vs baseline: 8.7538x; 1.2674x over previous
//
#include <hip/hip_runtime.h>
#include <math.h>

typedef __attribute__((ext_vector_type(8))) _Float16 half8;
typedef __attribute__((ext_vector_type(4))) _Float16 half4;
typedef __attribute__((ext_vector_type(4))) float    floatx4;

#define N_NODES 10000
#define M_PAD   10048      // 157 * 64
#define E_EDGES 160000
#define DIM     256
#define R_REL   237
#define L_LAYERS 6
#define B_BATCH 128
#define K_BATCH 33
#define K13     3328       // 13*256
#define KSPLIT  4
#define KSLICE  832        // K13/KSPLIT (halves)
#define KS_STEPS 26        // KSLICE/32
#define EPS_STD 1e-6f
#define EPS_LN  1e-5f

// async global->LDS, 16B per lane; LDS dest = wave-uniform base + lane*16
__device__ __forceinline__ void gload16(const void* g, void* lds) {
    __builtin_amdgcn_global_load_lds(
        (const __attribute__((address_space(1))) unsigned int*)g,
        (__attribute__((address_space(3))) unsigned int*)lds, 16, 0, 0);
}

// ---------------- CSR build ----------------
__global__ void hist_kernel(const int* __restrict__ dst, int* __restrict__ deg) {
    int e = blockIdx.x * blockDim.x + threadIdx.x;
    if (e < E_EDGES) atomicAdd(&deg[dst[e]], 1);
}

__global__ void scan_kernel(const int* __restrict__ deg_in, int* __restrict__ offs,
                            int* __restrict__ cursor, float* __restrict__ sum_log) {
    __shared__ int   part[1024];
    __shared__ float slog[1024];
    int t = threadIdx.x;
    const int CH = 10;
    int base = t * CH;
    int lsum = 0; float ls = 0.f;
    for (int j = 0; j < CH; j++) {
        int i = base + j;
        if (i < N_NODES) { int d = deg_in[i]; lsum += d; ls += logf((float)(d + 1)); }
    }
    part[t] = lsum; slog[t] = ls;
    __syncthreads();
    for (int off = 1; off < 1024; off <<= 1) {
        int v = (t >= off) ? part[t - off] : 0;
        __syncthreads();
        part[t] += v;
        __syncthreads();
    }
    int run = part[t] - lsum;
    for (int j = 0; j < CH; j++) {
        int i = base + j;
        if (i < N_NODES) { offs[i] = run; cursor[i] = run; run += deg_in[i]; }
    }
    __syncthreads();
    for (int off = 512; off > 0; off >>= 1) {
        if (t < off) slog[t] += slog[t + off];
        __syncthreads();
    }
    if (t == 0) sum_log[0] = slog[0];
}

__global__ void fill_kernel(const int* __restrict__ src, const int* __restrict__ dst,
                            const int* __restrict__ et, int* __restrict__ cursor,
                            int* __restrict__ csr_src, int* __restrict__ csr_et) {
    int e = blockIdx.x * blockDim.x + threadIdx.x;
    if (e < E_EDGES) {
        int d = dst[e];
        int p = atomicAdd(&cursor[d], 1);
        csr_src[p] = src[e];
        csr_et[p]  = et[e];
    }
}

__global__ void scales_kernel(const int* __restrict__ deg_in, const float* __restrict__ sum_log,
                              float* __restrict__ s1, float* __restrict__ s2) {
    int i = blockIdx.x * blockDim.x + threadIdx.x;
    if (i < N_NODES) {
        float mean = sum_log[0] * (1.0f / (float)N_NODES);
        float sc = logf((float)(deg_in[i] + 1)) / mean;
        s1[i] = sc;
        s2[i] = 1.0f / fmaxf(sc, 0.01f);
    }
}

// -------- W transpose + fp16 pack: Wt[l][n][k] = W[l][k][n] --------
__global__ void wt_kernel(const float* __restrict__ Ws, _Float16* __restrict__ Wt) {
    int idx = blockIdx.x * 256 + threadIdx.x;
    const int TOT = L_LAYERS * 256 * K13;
    if (idx >= TOT) return;
    int l = idx / (256 * K13);
    int r = idx - l * (256 * K13);
    int n = r / K13, k = r - n * K13;
    Wt[idx] = (_Float16)Ws[(size_t)l * K13 * 256 + (size_t)k * 256 + n];
}

// -------- fp32 -> fp16 converter --------
__global__ void cvt_kernel(const float* __restrict__ in, _Float16* __restrict__ outp, int n) {
    int i = blockIdx.x * 256 + threadIdx.x;
    if (i < n) outp[i] = (_Float16)in[i];
}

// ---- aggregation: one wave per node; fp16 gather, fp32 stats; emits fp16 A row ----
__global__ void agg_kernel(const float* __restrict__ x, const _Float16* __restrict__ xh,
                           const _Float16* __restrict__ relh,
                           const int* __restrict__ offs, const int* __restrict__ deg_in,
                           const int* __restrict__ csr_src, const int* __restrict__ csr_et,
                           const float* __restrict__ s1a, const float* __restrict__ s2a,
                           _Float16* __restrict__ Ah) {
    int wid  = threadIdx.x >> 6;
    int lane = threadIdx.x & 63;
    int node = blockIdx.x * 4 + wid;
    if (node >= N_NODES) return;
    int off = offs[node];
    int dc  = deg_in[node];
    const half4* xh4 = (const half4*)xh;
    const half4* rh4 = (const half4*)relh;
    float sx=0,sy=0,sz=0,sw=0, qx=0,qy=0,qz=0,qw=0;
    float mxx=-INFINITY,mxy=-INFINITY,mxz=-INFINITY,mxw=-INFINITY;
    float mnx= INFINITY,mny= INFINITY,mnz= INFINITY,mnw= INFINITY;
    for (int idx = off; idx < off + dc; idx++) {
        int s  = csr_src[idx];
        int et = csr_et[idx];
        half4 xv = xh4[(size_t)s * 64 + lane];
        half4 rv = rh4[(size_t)et * 64 + lane];
        float mx_ = (float)xv.x * (float)rv.x;
        float my_ = (float)xv.y * (float)rv.y;
        float mz_ = (float)xv.z * (float)rv.z;
        float mw_ = (float)xv.w * (float)rv.w;
        sx += mx_; sy += my_; sz += mz_; sw += mw_;
        qx += mx_*mx_; qy += my_*my_; qz += mz_*mz_; qw += mw_*mw_;
        mxx = fmaxf(mxx, mx_); mxy = fmaxf(mxy, my_); mxz = fmaxf(mxz, mz_); mxw = fmaxf(mxw, mw_);
        mnx = fminf(mnx, mx_); mny = fminf(mny, my_); mnz = fminf(mnz, mz_); mnw = fminf(mnw, mw_);
    }
    // self loop message = x (fp32, exact)
    float4 xself = ((const float4*)x)[(size_t)node * 64 + lane];
    sx += xself.x; sy += xself.y; sz += xself.z; sw += xself.w;
    qx += xself.x*xself.x; qy += xself.y*xself.y; qz += xself.z*xself.z; qw += xself.w*xself.w;
    mxx = fmaxf(mxx, xself.x); mxy = fmaxf(mxy, xself.y); mxz = fmaxf(mxz, xself.z); mxw = fmaxf(mxw, xself.w);
    mnx = fminf(mnx, xself.x); mny = fminf(mny, xself.y); mnz = fminf(mnz, xself.z); mnw = fminf(mnw, xself.w);

    float inv = 1.0f / (float)(dc + 1);
    float4 mean = {sx*inv, sy*inv, sz*inv, sw*inv};
    float4 mx = {mxx,mxy,mxz,mxw};
    float4 mn = {mnx,mny,mnz,mnw};
    float4 sd = {
        sqrtf(fmaxf(qx*inv - mean.x*mean.x, EPS_STD)),
        sqrtf(fmaxf(qy*inv - mean.y*mean.y, EPS_STD)),
        sqrtf(fmaxf(qz*inv - mean.z*mean.z, EPS_STD)),
        sqrtf(fmaxf(qw*inv - mean.w*mean.w, EPS_STD))};

    float s1v = s1a[node], s2v = s2a[node];
    half4* outp = (half4*)(Ah + (size_t)node * K13);
    // A col layout: k = (t*256+d)*3 + s  (t=feat type, d=dim, s=scale idx), then x at 3072+
    #pragma unroll
    for (int t = 0; t < 4; t++) {
        float4 v = (t == 0) ? mean : (t == 1 ? mx : (t == 2 ? mn : sd));
        int base = t * 192 + 3 * lane;
        half4 h0 = { (_Float16)v.x, (_Float16)(v.x*s1v), (_Float16)(v.x*s2v), (_Float16)v.y };
        half4 h1 = { (_Float16)(v.y*s1v), (_Float16)(v.y*s2v), (_Float16)v.z, (_Float16)(v.z*s1v) };
        half4 h2 = { (_Float16)(v.z*s2v), (_Float16)v.w, (_Float16)(v.w*s1v), (_Float16)(v.w*s2v) };
        outp[base] = h0; outp[base+1] = h1; outp[base+2] = h2;
    }
    half4 hx = { (_Float16)xself.x, (_Float16)xself.y, (_Float16)xself.z, (_Float16)xself.w };
    outp[768 + lane] = hx;
}

// ---------------- fp16 MFMA GEMM: 64x256 block, 4 waves, quad-buffered LDS ----------------
// counted-vmcnt pipeline (T3+T4): stage k+3 after barrier k, vmcnt(10) keeps 2 stages in flight
// grid = 157 m-blocks * KSPLIT = 628 blocks * 4 waves; LDS 80 KB -> 2 blocks/CU (8 waves/CU)
__launch_bounds__(256, 2)
__global__ void gemm_kernel(const _Float16* __restrict__ Ah, const _Float16* __restrict__ Wt,
                            float* __restrict__ hbuf) {
    __shared__ _Float16 sA[4][64 * 32];    // 16 KB
    __shared__ _Float16 sB[4][256 * 32];   // 64 KB

    const int tid  = threadIdx.x;
    const int lane = tid & 63;
    const int w    = tid >> 6;
    const int bx   = blockIdx.x;
    const int ks   = bx & 3;
    const int i0   = (bx >> 2) * 64;
    const int kbase = ks * KSLICE;

    const int row_l = lane & 15;
    const int kq    = lane >> 4;

    // LDS read offsets (halves), XOR chunk swizzle: chunk' = chunk ^ ((row>>1)&3)
    int a_off[4], b_off[4];
    #pragma unroll
    for (int rf = 0; rf < 4; rf++) {
        int r = rf * 16 + row_l;
        a_off[rf] = r * 32 + ((kq ^ ((r >> 1) & 3)) & 3) * 8;
    }
    #pragma unroll
    for (int cf = 0; cf < 4; cf++) {
        int n_ = w * 64 + cf * 16 + row_l;
        b_off[cf] = n_ * 32 + ((kq ^ ((n_ >> 1) & 3)) & 3) * 8;
    }

    // staging sources (pre-swizzled global address, linear LDS dest)
    int arow = w * 16 + (lane >> 2);
    int acol = (((lane & 3) ^ ((arow >> 1) & 3)) & 3) * 8;
    const char* a_src = (const char*)(Ah + (size_t)(i0 + arow) * K13 + kbase + acol);
    const char* b_src[4];
    #pragma unroll
    for (int q = 0; q < 4; q++) {
        int n_ = q * 64 + w * 16 + (lane >> 2);
        int c = (((lane & 3) ^ ((n_ >> 1) & 3)) & 3) * 8;
        b_src[q] = (const char*)(Wt + (size_t)n_ * K13 + kbase + c);
    }

    floatx4 acc[4][4];
    #pragma unroll
    for (int rf = 0; rf < 4; rf++)
        #pragma unroll
        for (int cf = 0; cf < 4; cf++)
            acc[rf][cf] = (floatx4){0.f, 0.f, 0.f, 0.f};

#define STAGE(BUF, S) do {                                                    \
    size_t koff_ = (size_t)(S) * 64; /* 32 halves * 2B */                     \
    gload16(a_src + koff_, (char*)(&sA[BUF][0]) + w * 1024);                  \
    gload16(b_src[0] + koff_, (char*)(&sB[BUF][0]) + (0 * 64 + w * 16) * 64); \
    gload16(b_src[1] + koff_, (char*)(&sB[BUF][0]) + (1 * 64 + w * 16) * 64); \
    gload16(b_src[2] + koff_, (char*)(&sB[BUF][0]) + (2 * 64 + w * 16) * 64); \
    gload16(b_src[3] + koff_, (char*)(&sB[BUF][0]) + (3 * 64 + w * 16) * 64); \
} while (0)

#define COMPUTE(CB) do {                                                      \
    half8 af[4], bf[4];                                                       \
    _Pragma("unroll")                                                         \
    for (int rf = 0; rf < 4; rf++) af[rf] = *(const half8*)(&sA[CB][a_off[rf]]); \
    _Pragma("unroll")                                                         \
    for (int cf = 0; cf < 4; cf++) bf[cf] = *(const half8*)(&sB[CB][b_off[cf]]); \
    __builtin_amdgcn_s_setprio(1);                                            \
    _Pragma("unroll")                                                         \
    for (int rf = 0; rf < 4; rf++)                                            \
        _Pragma("unroll")                                                     \
        for (int cf = 0; cf < 4; cf++)                                        \
            acc[rf][cf] = __builtin_amdgcn_mfma_f32_16x16x32_f16(af[rf], bf[cf], acc[rf][cf], 0, 0, 0); \
    __builtin_amdgcn_s_setprio(0);                                            \
} while (0)

    // prologue: stages 0,1,2 in flight (15 loads/wave)
    STAGE(0, 0);
    STAGE(1, 1);
    STAGE(2, 2);

    // main loop: steps 0..23. vmcnt(10) = 2 stages in flight -> stage s complete.
    for (int s = 0; s < 24; ++s) {
        asm volatile("s_waitcnt vmcnt(10)" ::: "memory");
        __builtin_amdgcn_s_barrier();
        if (s < 23) {
            int nb = (s + 3) & 3;
            STAGE(nb, s + 3);
        }
        int cb = s & 3;
        COMPUTE(cb);
    }
    // step 24 (buf 0): only stage 25 may remain in flight
    asm volatile("s_waitcnt vmcnt(5)" ::: "memory");
    __builtin_amdgcn_s_barrier();
    COMPUTE(0);
    // step 25 (buf 1): drain all
    asm volatile("s_waitcnt vmcnt(0)" ::: "memory");
    __builtin_amdgcn_s_barrier();
    COMPUTE(1);
#undef STAGE
#undef COMPUTE

    // C/D layout: col = lane&15, row = (lane>>4)*4 + j ; wave covers cols w*64..w*64+63
    float* outb = hbuf + (size_t)ks * M_PAD * 256;
    #pragma unroll
    for (int rf = 0; rf < 4; rf++) {
        #pragma unroll
        for (int j = 0; j < 4; j++) {
            int grow = i0 + rf * 16 + kq * 4 + j;
            float* orow = outb + (size_t)grow * 256 + w * 64;
            #pragma unroll
            for (int cf = 0; cf < 4; cf++)
                orow[cf * 16 + row_l] = acc[rf][cf][j];
        }
    }
}

// ---------------- 4-way reduce + bias + LN + relu + residual (+fp16 mirror) ----------------
__global__ void ln_kernel(const float* __restrict__ hbuf, const float* __restrict__ xin,
                          const float* __restrict__ bvec, const float* __restrict__ gvec,
                          const float* __restrict__ evec, float* __restrict__ xout,
                          _Float16* __restrict__ xhout) {
    int wid = threadIdx.x >> 6, lane = threadIdx.x & 63;
    int row = blockIdx.x * 4 + wid;
    if (row >= N_NODES) return;
    const float4* p0 = (const float4*)(hbuf + (size_t)row * 256);
    const float4* p1 = (const float4*)(hbuf + (size_t)M_PAD * 256     + (size_t)row * 256);
    const float4* p2 = (const float4*)(hbuf + (size_t)M_PAD * 256 * 2 + (size_t)row * 256);
    const float4* p3 = (const float4*)(hbuf + (size_t)M_PAD * 256 * 3 + (size_t)row * 256);
    float4 h0 = p0[lane], h1 = p1[lane], h2 = p2[lane], h3 = p3[lane];
    float4 bv = ((const float4*)bvec)[lane];
    float4 hv;
    hv.x = h0.x + h1.x + h2.x + h3.x + bv.x;
    hv.y = h0.y + h1.y + h2.y + h3.y + bv.y;
    hv.z = h0.z + h1.z + h2.z + h3.z + bv.z;
    hv.w = h0.w + h1.w + h2.w + h3.w + bv.w;
    float s = hv.x + hv.y + hv.z + hv.w;
    float qsq = hv.x*hv.x + hv.y*hv.y + hv.z*hv.z + hv.w*hv.w;
    #pragma unroll
    for (int off = 1; off < 64; off <<= 1) {
        s   += __shfl_xor(s, off);
        qsq += __shfl_xor(qsq, off);
    }
    float mu  = s * (1.0f / 256.0f);
    float var = qsq * (1.0f / 256.0f) - mu * mu;
    float rs  = rsqrtf(var + EPS_LN);
    float4 g = ((const float4*)gvec)[lane];
    float4 e = ((const float4*)evec)[lane];
    float4 xv = ((const float4*)(xin + (size_t)row * 256))[lane];
    float4 o;
    o.x = fmaxf((hv.x - mu) * rs * g.x + e.x, 0.f) + xv.x;
    o.y = fmaxf((hv.y - mu) * rs * g.y + e.y, 0.f) + xv.y;
    o.z = fmaxf((hv.z - mu) * rs * g.z + e.z, 0.f) + xv.z;
    o.w = fmaxf((hv.w - mu) * rs * g.w + e.w, 0.f) + xv.w;
    ((float4*)(xout + (size_t)row * 256))[lane] = o;
    half4 oh = { (_Float16)o.x, (_Float16)o.y, (_Float16)o.z, (_Float16)o.w };
    ((half4*)(xhout + (size_t)row * 256))[lane] = oh;
}

// ---------------- final scoring ----------------
__global__ void score_kernel(const float* __restrict__ x, const float* __restrict__ remb,
                             const int* __restrict__ batch, float* __restrict__ out) {
    int wid = threadIdx.x >> 6, lane = threadIdx.x & 63;
    int g = blockIdx.x * 4 + wid;
    if (g >= B_BATCH * K_BATCH) return;
    int si = batch[g * 3 + 0], ri = batch[g * 3 + 1], ti = batch[g * 3 + 2];
    const float4* xs = (const float4*)(x + (size_t)si * 256);
    const float4* xr = (const float4*)(remb + (size_t)ri * 256);
    const float4* xt = (const float4*)(x + (size_t)ti * 256);
    float4 a = xs[lane], r = xr[lane], t = xt[lane];
    float p = a.x*r.x*t.x + a.y*r.y*t.y + a.z*r.z*t.z + a.w*r.w*t.w;
    #pragma unroll
    for (int off = 1; off < 64; off <<= 1) p += __shfl_xor(p, off);
    if (lane == 0) out[g] = p;
}

extern "C" void kernel_launch(void* const* d_in, const int* in_sizes, int n_in,
                              void* d_out, int out_size, void* d_ws, size_t ws_size,
                              hipStream_t stream) {
    const float* x_in     = (const float*)d_in[0];
    const float* rel_embs = (const float*)d_in[1];
    const float* Ws       = (const float*)d_in[2];
    const float* bs       = (const float*)d_in[3];
    const float* ln_s     = (const float*)d_in[4];
    const float* ln_b     = (const float*)d_in[5];
    const float* remb     = (const float*)d_in[6];
    const int*   eidx     = (const int*)d_in[7];
    const int*   etype    = (const int*)d_in[8];
    const int*   batch    = (const int*)d_in[9];
    float* out = (float*)d_out;

    char* wp = (char*)d_ws;
    size_t o = 0;
    auto alloc = [&](size_t bytes) { void* p = wp + o; o += (bytes + 255) & ~255ull; return p; };
    int*      deg_in  = (int*)     alloc((size_t)N_NODES * 4);
    int*      offs    = (int*)     alloc((size_t)N_NODES * 4);
    int*      cursor  = (int*)     alloc((size_t)N_NODES * 4);
    float*    s1      = (float*)   alloc((size_t)N_NODES * 4);
    float*    s2      = (float*)   alloc((size_t)N_NODES * 4);
    float*    sum_log = (float*)   alloc(256);
    int*      csr_src = (int*)     alloc((size_t)E_EDGES * 4);
    int*      csr_et  = (int*)     alloc((size_t)E_EDGES * 4);
    _Float16* Ah      = (_Float16*)alloc((size_t)M_PAD * K13 * 2);            // 66.9 MB
    _Float16* Wt      = (_Float16*)alloc((size_t)L_LAYERS * 256 * K13 * 2);   // 10.2 MB
    float*    hbuf    = (float*)   alloc((size_t)KSPLIT * M_PAD * 256 * 4);   // 41.2 MB
    float*    xb0     = (float*)   alloc((size_t)M_PAD * 256 * 4);
    float*    xb1     = (float*)   alloc((size_t)M_PAD * 256 * 4);
    _Float16* xh0     = (_Float16*)alloc((size_t)M_PAD * 256 * 2);
    _Float16* xh1     = (_Float16*)alloc((size_t)M_PAD * 256 * 2);
    _Float16* relh    = (_Float16*)alloc((size_t)L_LAYERS * R_REL * 256 * 2); // 0.73 MB

    const int* src  = eidx;
    const int* dstp = eidx + E_EDGES;

    hipMemsetAsync(deg_in, 0, (size_t)N_NODES * 4, stream);
    hist_kernel<<<(E_EDGES + 255) / 256, 256, 0, stream>>>(dstp, deg_in);
    scan_kernel<<<1, 1024, 0, stream>>>(deg_in, offs, cursor, sum_log);
    fill_kernel<<<(E_EDGES + 255) / 256, 256, 0, stream>>>(src, dstp, etype, cursor, csr_src, csr_et);
    scales_kernel<<<(N_NODES + 255) / 256, 256, 0, stream>>>(deg_in, sum_log, s1, s2);
    {
        const int TOT = L_LAYERS * 256 * K13;
        wt_kernel<<<(TOT + 255) / 256, 256, 0, stream>>>(Ws, Wt);
        const int RT = L_LAYERS * R_REL * 256;
        cvt_kernel<<<(RT + 255) / 256, 256, 0, stream>>>(rel_embs, relh, RT);
        const int XT = N_NODES * 256;
        cvt_kernel<<<(XT + 255) / 256, 256, 0, stream>>>(x_in, xh0, XT);
    }
    hipMemcpyAsync(xb0, x_in, (size_t)N_NODES * 256 * 4, hipMemcpyDeviceToDevice, stream);

    float* xc = xb0; float* xn = xb1;
    _Float16* xhc = xh0; _Float16* xhn = xh1;
    for (int l = 0; l < L_LAYERS; l++) {
        agg_kernel<<<(N_NODES + 3) / 4, 256, 0, stream>>>(
            xc, xhc, relh + (size_t)l * R_REL * 256,
            offs, deg_in, csr_src, csr_et, s1, s2, Ah);
        gemm_kernel<<<157 * KSPLIT, 256, 0, stream>>>(Ah, Wt + (size_t)l * 256 * K13, hbuf);
        ln_kernel<<<(N_NODES + 3) / 4, 256, 0, stream>>>(
            hbuf, xc, bs + (size_t)l * 256, ln_s + (size_t)l * 256, ln_b + (size_t)l * 256, xn, xhn);
        float* t = xc; xc = xn; xn = t;
        _Float16* th = xhc; xhc = xhn; xhn = th;
    }
    score_kernel<<<(B_BATCH * K_BATCH + 3) / 4, 256, 0, stream>>>(xc, remb, batch, out);
}

// Round 7
// 556.793 us; speedup vs baseline: 9.7424x; 1.1129x over previous
//
#include <hip/hip_runtime.h>
#include <math.h>

typedef __attribute__((ext_vector_type(8))) _Float16 half8;
typedef __attribute__((ext_vector_type(4))) _Float16 half4;
typedef __attribute__((ext_vector_type(4))) float    floatx4;

#define N_NODES 10000
#define M_PAD   10048      // 157 * 64
#define E_EDGES 160000
#define DIM     256
#define R_REL   237
#define L_LAYERS 6
#define B_BATCH 128
#define K_BATCH 33
#define K13     3328       // 13*256
#define KSPLIT  4
#define KSLICE  832        // K13/KSPLIT (halves)
#define KS_STEPS 26        // KSLICE/32
#define EPS_STD 1e-6f
#define EPS_LN  1e-5f

// async global->LDS, 16B per lane; LDS dest = wave-uniform base + lane*16
__device__ __forceinline__ void gload16(const void* g, void* lds) {
    __builtin_amdgcn_global_load_lds(
        (const __attribute__((address_space(1))) unsigned int*)g,
        (__attribute__((address_space(3))) unsigned int*)lds, 16, 0, 0);
}

// ---------------- CSR build ----------------
__global__ void hist_kernel(const int* __restrict__ dst, int* __restrict__ deg) {
    int e = blockIdx.x * blockDim.x + threadIdx.x;
    if (e < E_EDGES) atomicAdd(&deg[dst[e]], 1);
}

__global__ void scan_kernel(const int* __restrict__ deg_in, int* __restrict__ offs,
                            int* __restrict__ cursor, float* __restrict__ sum_log) {
    __shared__ int   part[1024];
    __shared__ float slog[1024];
    int t = threadIdx.x;
    const int CH = 10;
    int base = t * CH;
    int lsum = 0; float ls = 0.f;
    for (int j = 0; j < CH; j++) {
        int i = base + j;
        if (i < N_NODES) { int d = deg_in[i]; lsum += d; ls += logf((float)(d + 1)); }
    }
    part[t] = lsum; slog[t] = ls;
    __syncthreads();
    for (int off = 1; off < 1024; off <<= 1) {
        int v = (t >= off) ? part[t - off] : 0;
        __syncthreads();
        part[t] += v;
        __syncthreads();
    }
    int run = part[t] - lsum;
    for (int j = 0; j < CH; j++) {
        int i = base + j;
        if (i < N_NODES) { offs[i] = run; cursor[i] = run; run += deg_in[i]; }
    }
    __syncthreads();
    for (int off = 512; off > 0; off >>= 1) {
        if (t < off) slog[t] += slog[t + off];
        __syncthreads();
    }
    if (t == 0) sum_log[0] = slog[0];
}

__global__ void fill_kernel(const int* __restrict__ src, const int* __restrict__ dst,
                            const int* __restrict__ et, int* __restrict__ cursor,
                            int* __restrict__ csr_src, int* __restrict__ csr_et) {
    int e = blockIdx.x * blockDim.x + threadIdx.x;
    if (e < E_EDGES) {
        int d = dst[e];
        int p = atomicAdd(&cursor[d], 1);
        csr_src[p] = src[e];
        csr_et[p]  = et[e];
    }
}

__global__ void scales_kernel(const int* __restrict__ deg_in, const float* __restrict__ sum_log,
                              float* __restrict__ s1, float* __restrict__ s2) {
    int i = blockIdx.x * blockDim.x + threadIdx.x;
    if (i < N_NODES) {
        float mean = sum_log[0] * (1.0f / (float)N_NODES);
        float sc = logf((float)(deg_in[i] + 1)) / mean;
        s1[i] = sc;
        s2[i] = 1.0f / fmaxf(sc, 0.01f);
    }
}

// -------- W permute+transpose to fp16: Wt[l][n][k'] = W[l][korig(k')][n] --------
// new A col order: k' = t*768 + s*256 + d  (t=feat type, s=scale idx, d=dim), x at 3072+
// original col:    korig = (t*256+d)*3 + s
__global__ void wt_kernel(const float* __restrict__ Ws, _Float16* __restrict__ Wt) {
    int idx = blockIdx.x * 256 + threadIdx.x;
    const int TOT = L_LAYERS * 256 * K13;
    if (idx >= TOT) return;
    int l = idx / (256 * K13);
    int r = idx - l * (256 * K13);
    int n = r / K13, k = r - n * K13;
    int korig;
    if (k < 3072) {
        int t = k / 768;
        int rem = k - t * 768;
        int s = rem >> 8;
        int d = rem & 255;
        korig = (t * 256 + d) * 3 + s;
    } else {
        korig = k;
    }
    Wt[idx] = (_Float16)Ws[(size_t)l * K13 * 256 + (size_t)korig * 256 + n];
}

// -------- fp32 -> fp16 converter --------
__global__ void cvt_kernel(const float* __restrict__ in, _Float16* __restrict__ outp, int n) {
    int i = blockIdx.x * 256 + threadIdx.x;
    if (i < n) outp[i] = (_Float16)in[i];
}

// ---- aggregation: one wave per node; fp16 gather, fp32 stats; emits fp16 feats (t-major) ----
__global__ void agg_kernel(const float* __restrict__ x, const _Float16* __restrict__ xh,
                           const _Float16* __restrict__ relh,
                           const int* __restrict__ offs, const int* __restrict__ deg_in,
                           const int* __restrict__ csr_src, const int* __restrict__ csr_et,
                           _Float16* __restrict__ feats) {
    int wid  = threadIdx.x >> 6;
    int lane = threadIdx.x & 63;
    int node = blockIdx.x * 4 + wid;
    if (node >= N_NODES) return;
    int off = offs[node];
    int dc  = deg_in[node];
    const half4* xh4 = (const half4*)xh;
    const half4* rh4 = (const half4*)relh;
    float sx=0,sy=0,sz=0,sw=0, qx=0,qy=0,qz=0,qw=0;
    float mxx=-INFINITY,mxy=-INFINITY,mxz=-INFINITY,mxw=-INFINITY;
    float mnx= INFINITY,mny= INFINITY,mnz= INFINITY,mnw= INFINITY;
    for (int idx = off; idx < off + dc; idx++) {
        int s  = csr_src[idx];
        int et = csr_et[idx];
        half4 xv = xh4[(size_t)s * 64 + lane];
        half4 rv = rh4[(size_t)et * 64 + lane];
        float mx_ = (float)xv.x * (float)rv.x;
        float my_ = (float)xv.y * (float)rv.y;
        float mz_ = (float)xv.z * (float)rv.z;
        float mw_ = (float)xv.w * (float)rv.w;
        sx += mx_; sy += my_; sz += mz_; sw += mw_;
        qx += mx_*mx_; qy += my_*my_; qz += mz_*mz_; qw += mw_*mw_;
        mxx = fmaxf(mxx, mx_); mxy = fmaxf(mxy, my_); mxz = fmaxf(mxz, mz_); mxw = fmaxf(mxw, mw_);
        mnx = fminf(mnx, mx_); mny = fminf(mny, my_); mnz = fminf(mnz, mz_); mnw = fminf(mnw, mw_);
    }
    // self loop message = x (fp32, exact)
    float4 xself = ((const float4*)x)[(size_t)node * 64 + lane];
    sx += xself.x; sy += xself.y; sz += xself.z; sw += xself.w;
    qx += xself.x*xself.x; qy += xself.y*xself.y; qz += xself.z*xself.z; qw += xself.w*xself.w;
    mxx = fmaxf(mxx, xself.x); mxy = fmaxf(mxy, xself.y); mxz = fmaxf(mxz, xself.z); mxw = fmaxf(mxw, xself.w);
    mnx = fminf(mnx, xself.x); mny = fminf(mny, xself.y); mnz = fminf(mnz, xself.z); mnw = fminf(mnw, xself.w);

    float inv = 1.0f / (float)(dc + 1);
    float4 mean = {sx*inv, sy*inv, sz*inv, sw*inv};
    float4 sd = {
        sqrtf(fmaxf(qx*inv - mean.x*mean.x, EPS_STD)),
        sqrtf(fmaxf(qy*inv - mean.y*mean.y, EPS_STD)),
        sqrtf(fmaxf(qz*inv - mean.z*mean.z, EPS_STD)),
        sqrtf(fmaxf(qw*inv - mean.w*mean.w, EPS_STD))};

    half4* fout = (half4*)(feats + (size_t)node * 1024);
    half4 hm = { (_Float16)mean.x, (_Float16)mean.y, (_Float16)mean.z, (_Float16)mean.w };
    half4 hx = { (_Float16)mxx, (_Float16)mxy, (_Float16)mxz, (_Float16)mxw };
    half4 hn = { (_Float16)mnx, (_Float16)mny, (_Float16)mnz, (_Float16)mnw };
    half4 hs = { (_Float16)sd.x, (_Float16)sd.y, (_Float16)sd.z, (_Float16)sd.w };
    fout[lane]        = hm;   // t=0 mean
    fout[64  + lane]  = hx;   // t=1 max
    fout[128 + lane]  = hn;   // t=2 min
    fout[192 + lane]  = hs;   // t=3 std
}

// ---------------- fp16 MFMA GEMM: 64x256 block, 4 waves, 3-buffer counted-vmcnt ----------------
// A reg-staged (scale folded at stage time), B via global_load_lds; vmcnt(5) steady state.
__launch_bounds__(256, 2)
__global__ void gemm_kernel(const _Float16* __restrict__ feats, const _Float16* __restrict__ xh,
                            const _Float16* __restrict__ Wt, const float* __restrict__ s1a,
                            const float* __restrict__ s2a, _Float16* __restrict__ hbuf) {
    __shared__ _Float16 sA[3][64 * 32];    // 12 KB
    __shared__ _Float16 sB[3][256 * 32];   // 48 KB

    // bijective ks-major XCD swizzle over 628 blocks (q=78, r=4): lin = ks*157 + m
    const int q_ = 78, r_ = 4;
    int xcd = blockIdx.x & 7, loc = blockIdx.x >> 3;
    int lin = (xcd < r_ ? xcd * (q_ + 1) : r_ * (q_ + 1) + (xcd - r_) * q_) + loc;
    int ks = lin / 157;
    int m  = lin - ks * 157;
    const int i0    = m * 64;
    const int kbase = ks * KSLICE;

    const int tid   = threadIdx.x;
    const int lane  = tid & 63;
    const int w     = tid >> 6;
    const int row_l = lane & 15;
    const int kq    = lane >> 4;

    // reader LDS offsets (halves), XOR chunk swizzle: chunk' = chunk ^ ((row>>1)&3)
    int a_off[4], b_off[4];
    #pragma unroll
    for (int rf = 0; rf < 4; rf++) {
        int r = rf * 16 + row_l;
        a_off[rf] = r * 32 + ((kq ^ ((r >> 1) & 3)) & 3) * 8;
    }
    #pragma unroll
    for (int cf = 0; cf < 4; cf++) {
        int n_ = w * 64 + cf * 16 + row_l;
        b_off[cf] = n_ * 32 + ((kq ^ ((n_ >> 1) & 3)) & 3) * 8;
    }

    // ---- A staging role: thread -> (row, k-chunk); swizzled LDS slot, unswizzled source ----
    const int arow = tid >> 2;                       // 0..63
    const int ac   = tid & 3;                        // global 8-half chunk
    const int aswz = ac ^ ((arow >> 1) & 3);
    const float s1v = s1a[i0 + arow];
    const float s2v = s2a[i0 + arow];
    const _Float16* fbase = feats + (size_t)(i0 + arow) * 1024 + ac * 8;
    const _Float16* xbase = xh    + (size_t)(i0 + arow) * 256  + ac * 8;

    // ---- B staging (pre-swizzled global source, linear LDS dest via gload16) ----
    const char* b_src[4];
    #pragma unroll
    for (int q = 0; q < 4; q++) {
        int n_ = q * 64 + w * 16 + (lane >> 2);
        int c = (((lane & 3) ^ ((n_ >> 1) & 3)) & 3) * 8;
        b_src[q] = (const char*)(Wt + (size_t)n_ * K13 + kbase + c);
    }

    floatx4 acc[4][4];
    #pragma unroll
    for (int rf = 0; rf < 4; rf++)
        #pragma unroll
        for (int cf = 0; cf < 4; cf++)
            acc[rf][cf] = (floatx4){0.f, 0.f, 0.f, 0.f};

    half8 areg[3];

    // per-stage source address + scale (wave-uniform selector, runtime ks)
#define A_ADDR(S, PTR, SCF) do {                                              \
    int k0_ = kbase + (S) * 32;                                               \
    if (k0_ < 3072) {                                                         \
        int t_ = k0_ / 768;                                                   \
        int rem_ = k0_ - t_ * 768;                                            \
        int sI_ = rem_ >> 8;                                                  \
        int d0_ = rem_ & 255;                                                 \
        PTR = fbase + t_ * 256 + d0_;                                         \
        SCF = (sI_ == 0) ? 1.0f : (sI_ == 1 ? s1v : s2v);                     \
    } else {                                                                  \
        PTR = xbase + (k0_ - 3072);                                           \
        SCF = 1.0f;                                                           \
    }                                                                         \
} while (0)

#define ALOAD(S, REG) do {                                                    \
    const _Float16* p_; float sc_;                                            \
    A_ADDR(S, p_, sc_);                                                       \
    REG = *(const half8*)p_;                                                  \
} while (0)

#define BSTAGE(BUF, S) do {                                                   \
    size_t koff_ = (size_t)(S) * 64; /* 32 halves * 2B */                     \
    gload16(b_src[0] + koff_, (char*)(&sB[BUF][0]) + (0 * 64 + w * 16) * 64); \
    gload16(b_src[1] + koff_, (char*)(&sB[BUF][0]) + (1 * 64 + w * 16) * 64); \
    gload16(b_src[2] + koff_, (char*)(&sB[BUF][0]) + (2 * 64 + w * 16) * 64); \
    gload16(b_src[3] + koff_, (char*)(&sB[BUF][0]) + (3 * 64 + w * 16) * 64); \
} while (0)

#define AWRITE(BUF, S, REG) do {                                              \
    const _Float16* p_; float sc_;                                            \
    A_ADDR(S, p_, sc_);  /* only sc_ used; addr math folds */                 \
    half8 v_ = REG * (_Float16)sc_;                                           \
    *(half8*)(&sA[BUF][arow * 32 + aswz * 8]) = v_;                           \
} while (0)

#define COMPUTE(CB) do {                                                      \
    half8 af[4], bf[4];                                                       \
    _Pragma("unroll")                                                         \
    for (int rf = 0; rf < 4; rf++) af[rf] = *(const half8*)(&sA[CB][a_off[rf]]); \
    _Pragma("unroll")                                                         \
    for (int cf = 0; cf < 4; cf++) bf[cf] = *(const half8*)(&sB[CB][b_off[cf]]); \
    __builtin_amdgcn_s_setprio(1);                                            \
    _Pragma("unroll")                                                         \
    for (int rf = 0; rf < 4; rf++)                                            \
        _Pragma("unroll")                                                     \
        for (int cf = 0; cf < 4; cf++)                                        \
            acc[rf][cf] = __builtin_amdgcn_mfma_f32_16x16x32_f16(af[rf], bf[cf], acc[rf][cf], 0, 0, 0); \
    __builtin_amdgcn_s_setprio(0);                                            \
} while (0)

    // prologue: stages 0,1 issued (A->reg, B->LDS); 5 vm-ops each, issue order A,B,B,B,B
    ALOAD(0, areg[0]); BSTAGE(0, 0);
    ALOAD(1, areg[1]); BSTAGE(1, 1);

    // main loop, steps 0..24: counted vmcnt(5) = newest stage may remain in flight
    #pragma unroll
    for (int s = 0; s < 25; ++s) {
        asm volatile("s_waitcnt vmcnt(5)" ::: "memory");   // stage s fully arrived
        AWRITE(s % 3, s, areg[s % 3]);                      // scale-fold + ds_write
        asm volatile("s_waitcnt lgkmcnt(0)" ::: "memory"); // ds_write visible
        __builtin_amdgcn_sched_barrier(0);
        __builtin_amdgcn_s_barrier();                      // all waves staged buf s%3
        if (s + 2 < KS_STEPS) {
            ALOAD(s + 2, areg[(s + 2) % 3]);
            BSTAGE((s + 2) % 3, s + 2);
        }
        COMPUTE(s % 3);
    }
    // peeled step 25: drain
    asm volatile("s_waitcnt vmcnt(0)" ::: "memory");
    AWRITE(25 % 3, 25, areg[25 % 3]);
    asm volatile("s_waitcnt lgkmcnt(0)" ::: "memory");
    __builtin_amdgcn_sched_barrier(0);
    __builtin_amdgcn_s_barrier();
    COMPUTE(25 % 3);

#undef A_ADDR
#undef ALOAD
#undef BSTAGE
#undef AWRITE
#undef COMPUTE

    // C/D layout: col = lane&15, row = (lane>>4)*4 + j ; wave covers cols w*64..w*64+63
    // fp16 partials: 16 lanes x 2B contiguous per (rf,j,cf); cf-chunks complete 128B lines
    _Float16* outb = hbuf + (size_t)ks * M_PAD * 256;
    #pragma unroll
    for (int rf = 0; rf < 4; rf++) {
        #pragma unroll
        for (int j = 0; j < 4; j++) {
            int grow = i0 + rf * 16 + kq * 4 + j;
            _Float16* orow = outb + (size_t)grow * 256 + w * 64;
            #pragma unroll
            for (int cf = 0; cf < 4; cf++)
                orow[cf * 16 + row_l] = (_Float16)acc[rf][cf][j];
        }
    }
}

// ---------------- 4-way reduce + bias + LN + relu + residual (+fp16 mirror) ----------------
__global__ void ln_kernel(const _Float16* __restrict__ hbuf, const float* __restrict__ xin,
                          const float* __restrict__ bvec, const float* __restrict__ gvec,
                          const float* __restrict__ evec, float* __restrict__ xout,
                          _Float16* __restrict__ xhout) {
    int wid = threadIdx.x >> 6, lane = threadIdx.x & 63;
    int row = blockIdx.x * 4 + wid;
    if (row >= N_NODES) return;
    const half4* p0 = (const half4*)(hbuf + (size_t)row * 256);
    const half4* p1 = (const half4*)(hbuf + (size_t)M_PAD * 256     + (size_t)row * 256);
    const half4* p2 = (const half4*)(hbuf + (size_t)M_PAD * 256 * 2 + (size_t)row * 256);
    const half4* p3 = (const half4*)(hbuf + (size_t)M_PAD * 256 * 3 + (size_t)row * 256);
    half4 h0 = p0[lane], h1 = p1[lane], h2 = p2[lane], h3 = p3[lane];
    float4 bv = ((const float4*)bvec)[lane];
    float4 hv;
    hv.x = (float)h0.x + (float)h1.x + (float)h2.x + (float)h3.x + bv.x;
    hv.y = (float)h0.y + (float)h1.y + (float)h2.y + (float)h3.y + bv.y;
    hv.z = (float)h0.z + (float)h1.z + (float)h2.z + (float)h3.z + bv.z;
    hv.w = (float)h0.w + (float)h1.w + (float)h2.w + (float)h3.w + bv.w;
    float s = hv.x + hv.y + hv.z + hv.w;
    float qsq = hv.x*hv.x + hv.y*hv.y + hv.z*hv.z + hv.w*hv.w;
    #pragma unroll
    for (int off = 1; off < 64; off <<= 1) {
        s   += __shfl_xor(s, off);
        qsq += __shfl_xor(qsq, off);
    }
    float mu  = s * (1.0f / 256.0f);
    float var = qsq * (1.0f / 256.0f) - mu * mu;
    float rs  = rsqrtf(var + EPS_LN);
    float4 g = ((const float4*)gvec)[lane];
    float4 e = ((const float4*)evec)[lane];
    float4 xv = ((const float4*)(xin + (size_t)row * 256))[lane];
    float4 o;
    o.x = fmaxf((hv.x - mu) * rs * g.x + e.x, 0.f) + xv.x;
    o.y = fmaxf((hv.y - mu) * rs * g.y + e.y, 0.f) + xv.y;
    o.z = fmaxf((hv.z - mu) * rs * g.z + e.z, 0.f) + xv.z;
    o.w = fmaxf((hv.w - mu) * rs * g.w + e.w, 0.f) + xv.w;
    ((float4*)(xout + (size_t)row * 256))[lane] = o;
    half4 oh = { (_Float16)o.x, (_Float16)o.y, (_Float16)o.z, (_Float16)o.w };
    ((half4*)(xhout + (size_t)row * 256))[lane] = oh;
}

// ---------------- final scoring ----------------
__global__ void score_kernel(const float* __restrict__ x, const float* __restrict__ remb,
                             const int* __restrict__ batch, float* __restrict__ out) {
    int wid = threadIdx.x >> 6, lane = threadIdx.x & 63;
    int g = blockIdx.x * 4 + wid;
    if (g >= B_BATCH * K_BATCH) return;
    int si = batch[g * 3 + 0], ri = batch[g * 3 + 1], ti = batch[g * 3 + 2];
    const float4* xs = (const float4*)(x + (size_t)si * 256);
    const float4* xr = (const float4*)(remb + (size_t)ri * 256);
    const float4* xt = (const float4*)(x + (size_t)ti * 256);
    float4 a = xs[lane], r = xr[lane], t = xt[lane];
    float p = a.x*r.x*t.x + a.y*r.y*t.y + a.z*r.z*t.z + a.w*r.w*t.w;
    #pragma unroll
    for (int off = 1; off < 64; off <<= 1) p += __shfl_xor(p, off);
    if (lane == 0) out[g] = p;
}

extern "C" void kernel_launch(void* const* d_in, const int* in_sizes, int n_in,
                              void* d_out, int out_size, void* d_ws, size_t ws_size,
                              hipStream_t stream) {
    const float* x_in     = (const float*)d_in[0];
    const float* rel_embs = (const float*)d_in[1];
    const float* Ws       = (const float*)d_in[2];
    const float* bs       = (const float*)d_in[3];
    const float* ln_s     = (const float*)d_in[4];
    const float* ln_b     = (const float*)d_in[5];
    const float* remb     = (const float*)d_in[6];
    const int*   eidx     = (const int*)d_in[7];
    const int*   etype    = (const int*)d_in[8];
    const int*   batch    = (const int*)d_in[9];
    float* out = (float*)d_out;

    char* wp = (char*)d_ws;
    size_t o = 0;
    auto alloc = [&](size_t bytes) { void* p = wp + o; o += (bytes + 255) & ~255ull; return p; };
    int*      deg_in  = (int*)     alloc((size_t)N_NODES * 4);
    int*      offs    = (int*)     alloc((size_t)N_NODES * 4);
    int*      cursor  = (int*)     alloc((size_t)N_NODES * 4);
    float*    s1      = (float*)   alloc((size_t)M_PAD * 4);
    float*    s2      = (float*)   alloc((size_t)M_PAD * 4);
    float*    sum_log = (float*)   alloc(256);
    int*      csr_src = (int*)     alloc((size_t)E_EDGES * 4);
    int*      csr_et  = (int*)     alloc((size_t)E_EDGES * 4);
    _Float16* feats   = (_Float16*)alloc((size_t)M_PAD * 1024 * 2);           // 20.6 MB
    _Float16* Wt      = (_Float16*)alloc((size_t)L_LAYERS * 256 * K13 * 2);   // 10.2 MB
    _Float16* hbuf    = (_Float16*)alloc((size_t)KSPLIT * M_PAD * 256 * 2);   // 20.6 MB
    float*    xb0     = (float*)   alloc((size_t)M_PAD * 256 * 4);
    float*    xb1     = (float*)   alloc((size_t)M_PAD * 256 * 4);
    _Float16* xh0     = (_Float16*)alloc((size_t)M_PAD * 256 * 2);
    _Float16* xh1     = (_Float16*)alloc((size_t)M_PAD * 256 * 2);
    _Float16* relh    = (_Float16*)alloc((size_t)L_LAYERS * R_REL * 256 * 2); // 0.73 MB

    const int* src  = eidx;
    const int* dstp = eidx + E_EDGES;

    hipMemsetAsync(deg_in, 0, (size_t)N_NODES * 4, stream);
    hist_kernel<<<(E_EDGES + 255) / 256, 256, 0, stream>>>(dstp, deg_in);
    scan_kernel<<<1, 1024, 0, stream>>>(deg_in, offs, cursor, sum_log);
    fill_kernel<<<(E_EDGES + 255) / 256, 256, 0, stream>>>(src, dstp, etype, cursor, csr_src, csr_et);
    scales_kernel<<<(N_NODES + 255) / 256, 256, 0, stream>>>(deg_in, sum_log, s1, s2);
    {
        const int TOT = L_LAYERS * 256 * K13;
        wt_kernel<<<(TOT + 255) / 256, 256, 0, stream>>>(Ws, Wt);
        const int RT = L_LAYERS * R_REL * 256;
        cvt_kernel<<<(RT + 255) / 256, 256, 0, stream>>>(rel_embs, relh, RT);
        const int XT = N_NODES * 256;
        cvt_kernel<<<(XT + 255) / 256, 256, 0, stream>>>(x_in, xh0, XT);
    }
    hipMemcpyAsync(xb0, x_in, (size_t)N_NODES * 256 * 4, hipMemcpyDeviceToDevice, stream);

    float* xc = xb0; float* xn = xb1;
    _Float16* xhc = xh0; _Float16* xhn = xh1;
    for (int l = 0; l < L_LAYERS; l++) {
        agg_kernel<<<(N_NODES + 3) / 4, 256, 0, stream>>>(
            xc, xhc, relh + (size_t)l * R_REL * 256,
            offs, deg_in, csr_src, csr_et, feats);
        gemm_kernel<<<157 * KSPLIT, 256, 0, stream>>>(
            feats, xhc, Wt + (size_t)l * 256 * K13, s1, s2, hbuf);
        ln_kernel<<<(N_NODES + 3) / 4, 256, 0, stream>>>(
            hbuf, xc, bs + (size_t)l * 256, ln_s + (size_t)l * 256, ln_b + (size_t)l * 256, xn, xhn);
        float* t = xc; xc = xn; xn = t;
        _Float16* th = xhc; xhc = xhn; xhn = th;
    }
    score_kernel<<<(B_BATCH * K_BATCH + 3) / 4, 256, 0, stream>>>(xc, remb, batch, out);
}

// Round 8
// 539.840 us; speedup vs baseline: 10.0483x; 1.0314x over previous
//
#include <hip/hip_runtime.h>
#include <math.h>

typedef __attribute__((ext_vector_type(8))) _Float16 half8;
typedef __attribute__((ext_vector_type(4))) _Float16 half4;
typedef __attribute__((ext_vector_type(4))) float    floatx4;

#define N_NODES 10000
#define M_PAD   10048      // 157 * 64
#define E_EDGES 160000
#define DIM     256
#define R_REL   237
#define L_LAYERS 6
#define B_BATCH 128
#define K_BATCH 33
#define K13     3328       // 13*256
#define KSPLIT  4
#define KSLICE  832        // K13/KSPLIT (halves)
#define KS_STEPS 26        // KSLICE/32
#define EPS_STD 1e-6f
#define EPS_LN  1e-5f

// async global->LDS, 16B per lane; LDS dest = wave-uniform base + lane*16
__device__ __forceinline__ void gload16(const void* g, void* lds) {
    __builtin_amdgcn_global_load_lds(
        (const __attribute__((address_space(1))) unsigned int*)g,
        (__attribute__((address_space(3))) unsigned int*)lds, 16, 0, 0);
}

// ---------------- CSR build ----------------
__global__ void hist_kernel(const int* __restrict__ dst, int* __restrict__ deg) {
    int e = blockIdx.x * blockDim.x + threadIdx.x;
    if (e < E_EDGES) atomicAdd(&deg[dst[e]], 1);
}

__global__ void scan_kernel(const int* __restrict__ deg_in, int* __restrict__ offs,
                            int* __restrict__ cursor, float* __restrict__ sum_log) {
    __shared__ int   part[1024];
    __shared__ float slog[1024];
    int t = threadIdx.x;
    const int CH = 10;
    int base = t * CH;
    int lsum = 0; float ls = 0.f;
    for (int j = 0; j < CH; j++) {
        int i = base + j;
        if (i < N_NODES) { int d = deg_in[i]; lsum += d; ls += logf((float)(d + 1)); }
    }
    part[t] = lsum; slog[t] = ls;
    __syncthreads();
    for (int off = 1; off < 1024; off <<= 1) {
        int v = (t >= off) ? part[t - off] : 0;
        __syncthreads();
        part[t] += v;
        __syncthreads();
    }
    int run = part[t] - lsum;
    for (int j = 0; j < CH; j++) {
        int i = base + j;
        if (i < N_NODES) { offs[i] = run; cursor[i] = run; run += deg_in[i]; }
    }
    __syncthreads();
    for (int off = 512; off > 0; off >>= 1) {
        if (t < off) slog[t] += slog[t + off];
        __syncthreads();
    }
    if (t == 0) sum_log[0] = slog[0];
}

__global__ void fill_kernel(const int* __restrict__ src, const int* __restrict__ dst,
                            const int* __restrict__ et, int* __restrict__ cursor,
                            int* __restrict__ csr_src, int* __restrict__ csr_et) {
    int e = blockIdx.x * blockDim.x + threadIdx.x;
    if (e < E_EDGES) {
        int d = dst[e];
        int p = atomicAdd(&cursor[d], 1);
        csr_src[p] = src[e];
        csr_et[p]  = et[e];
    }
}

__global__ void scales_kernel(const int* __restrict__ deg_in, const float* __restrict__ sum_log,
                              float* __restrict__ s1, float* __restrict__ s2) {
    int i = blockIdx.x * blockDim.x + threadIdx.x;
    if (i < N_NODES) {
        float mean = sum_log[0] * (1.0f / (float)N_NODES);
        float sc = logf((float)(deg_in[i] + 1)) / mean;
        s1[i] = sc;
        s2[i] = 1.0f / fmaxf(sc, 0.01f);
    }
}

// -------- W permute+transpose to fp16: Wt[l][n][k'] = W[l][korig(k')][n] --------
// new A col order: k' = t*768 + s*256 + d, x at 3072+; korig = (t*256+d)*3 + s
__global__ void wt_kernel(const float* __restrict__ Ws, _Float16* __restrict__ Wt) {
    int idx = blockIdx.x * 256 + threadIdx.x;
    const int TOT = L_LAYERS * 256 * K13;
    if (idx >= TOT) return;
    int l = idx / (256 * K13);
    int r = idx - l * (256 * K13);
    int n = r / K13, k = r - n * K13;
    int korig;
    if (k < 3072) {
        int t = k / 768;
        int rem = k - t * 768;
        int s = rem >> 8;
        int d = rem & 255;
        korig = (t * 256 + d) * 3 + s;
    } else {
        korig = k;
    }
    Wt[idx] = (_Float16)Ws[(size_t)l * K13 * 256 + (size_t)korig * 256 + n];
}

// -------- fp32 -> fp16 converter --------
__global__ void cvt_kernel(const float* __restrict__ in, _Float16* __restrict__ outp, int n) {
    int i = blockIdx.x * 256 + threadIdx.x;
    if (i < n) outp[i] = (_Float16)in[i];
}

// ---- aggregation: one wave per node, 2 edges/iteration (lane halves), fp16 gather ----
__global__ void agg_kernel(const float* __restrict__ x, const _Float16* __restrict__ xh,
                           const _Float16* __restrict__ relh,
                           const int* __restrict__ offs, const int* __restrict__ deg_in,
                           const int* __restrict__ csr_src, const int* __restrict__ csr_et,
                           _Float16* __restrict__ feats) {
    int wid  = threadIdx.x >> 6;
    int lane = threadIdx.x & 63;
    int node = blockIdx.x * 4 + wid;
    if (node >= N_NODES) return;
    int half = lane >> 5;         // 0: even edges, 1: odd edges
    int sub  = lane & 31;         // 8-dim chunk owner: dims sub*8..sub*8+7
    int off = offs[node];
    int end = off + deg_in[node];
    const half8* xh8 = (const half8*)xh;
    const half8* rh8 = (const half8*)relh;

    float s_[8], q_[8], mx_[8], mn_[8];
    #pragma unroll
    for (int i = 0; i < 8; i++) { s_[i] = 0.f; q_[i] = 0.f; mx_[i] = -INFINITY; mn_[i] = INFINITY; }

    for (int base = off; base < end; base += 2) {
        int e = base + half;
        if (e < end) {
            int sN = csr_src[e];
            int et = csr_et[e];
            half8 xv = xh8[(size_t)sN * 32 + sub];
            half8 rv = rh8[(size_t)et * 32 + sub];
            #pragma unroll
            for (int i = 0; i < 8; i++) {
                float m = (float)xv[i] * (float)rv[i];
                s_[i] += m; q_[i] += m * m;
                mx_[i] = fmaxf(mx_[i], m);
                mn_[i] = fminf(mn_[i], m);
            }
        }
    }
    // combine halves (both halves end up with full stats)
    #pragma unroll
    for (int i = 0; i < 8; i++) {
        s_[i] += __shfl_xor(s_[i], 32);
        q_[i] += __shfl_xor(q_[i], 32);
        mx_[i] = fmaxf(mx_[i], __shfl_xor(mx_[i], 32));
        mn_[i] = fminf(mn_[i], __shfl_xor(mn_[i], 32));
    }
    // self loop message = x (fp32, exact); dims sub*8..sub*8+7
    const float4* xrow = (const float4*)(x + (size_t)node * 256);
    float4 xa = xrow[sub * 2], xb = xrow[sub * 2 + 1];
    float xs[8] = {xa.x, xa.y, xa.z, xa.w, xb.x, xb.y, xb.z, xb.w};
    #pragma unroll
    for (int i = 0; i < 8; i++) {
        s_[i] += xs[i]; q_[i] += xs[i] * xs[i];
        mx_[i] = fmaxf(mx_[i], xs[i]);
        mn_[i] = fminf(mn_[i], xs[i]);
    }
    float inv = 1.0f / (float)(end - off + 1);
    half8 hm, hx, hn, hs;
    #pragma unroll
    for (int i = 0; i < 8; i++) {
        float mean = s_[i] * inv;
        float sd = sqrtf(fmaxf(q_[i] * inv - mean * mean, EPS_STD));
        hm[i] = (_Float16)mean; hx[i] = (_Float16)mx_[i];
        hn[i] = (_Float16)mn_[i]; hs[i] = (_Float16)sd;
    }
    half8* fout = (half8*)(feats + (size_t)node * 1024);
    if (half == 0) {
        fout[0 * 32 + sub] = hm;   // t=0 mean
        fout[1 * 32 + sub] = hx;   // t=1 max
    } else {
        fout[2 * 32 + sub] = hn;   // t=2 min
        fout[3 * 32 + sub] = hs;   // t=3 std
    }
}

// ---------------- fp16 MFMA GEMM: 64x128 tiles, 4 waves, 3-buffer counted-vmcnt ----------------
// grid = 157 m * 2 n * 4 ks = 1256 blocks (8*157 -> exact XCD swizzle); 36 KB LDS -> 4 blocks/CU
__launch_bounds__(256, 4)
__global__ void gemm_kernel(const _Float16* __restrict__ feats, const _Float16* __restrict__ xh,
                            const _Float16* __restrict__ Wt, const float* __restrict__ s1a,
                            const float* __restrict__ s2a, _Float16* __restrict__ hbuf) {
    __shared__ _Float16 sA[3][64 * 32];    // 12 KB
    __shared__ _Float16 sB[3][128 * 32];   // 24 KB

    // XCD swizzle: 1256 = 8*157; lin enumerates (ks,nh)-major, m-minor
    int xcd = blockIdx.x & 7, loc = blockIdx.x >> 3;
    int lin = xcd * 157 + loc;
    int ks  = lin / 314;
    int rem = lin - ks * 314;
    int nh  = rem / 157;
    int m   = rem - nh * 157;
    const int i0    = m * 64;
    const int n0    = nh * 128;
    const int kbase = ks * KSLICE;

    const int tid   = threadIdx.x;
    const int lane  = tid & 63;
    const int w     = tid >> 6;
    const int row_l = lane & 15;
    const int kq    = lane >> 4;

    // reader LDS offsets (halves), XOR chunk swizzle: chunk' = chunk ^ ((row>>1)&3)
    int a_off[4], b_off[2];
    #pragma unroll
    for (int rf = 0; rf < 4; rf++) {
        int r = rf * 16 + row_l;
        a_off[rf] = r * 32 + ((kq ^ ((r >> 1) & 3)) & 3) * 8;
    }
    #pragma unroll
    for (int cf = 0; cf < 2; cf++) {
        int n_ = w * 32 + cf * 16 + row_l;           // local col 0..127
        b_off[cf] = n_ * 32 + ((kq ^ ((n_ >> 1) & 3)) & 3) * 8;
    }

    // ---- A staging role: thread -> (row, k-chunk); swizzled LDS slot, raw source ----
    const int arow = tid >> 2;
    const int ac   = tid & 3;
    const int aswz = ac ^ ((arow >> 1) & 3);
    const float s1v = s1a[i0 + arow];
    const float s2v = s2a[i0 + arow];
    const _Float16* fbase = feats + (size_t)(i0 + arow) * 1024 + ac * 8;
    const _Float16* xbase = xh    + (size_t)(i0 + arow) * 256  + ac * 8;

    // ---- B staging: 128 rows, 2 gload16 per wave; pre-swizzled source, linear dest ----
    const char* b_src[2];
    #pragma unroll
    for (int j = 0; j < 2; j++) {
        int rloc = j * 64 + w * 16 + (lane >> 2);    // local row 0..127
        int c = (lane & 3) ^ ((rloc >> 1) & 3);
        b_src[j] = (const char*)(Wt + (size_t)(n0 + rloc) * K13 + kbase + c * 8);
    }

    floatx4 acc[4][2];
    #pragma unroll
    for (int rf = 0; rf < 4; rf++)
        #pragma unroll
        for (int cf = 0; cf < 2; cf++)
            acc[rf][cf] = (floatx4){0.f, 0.f, 0.f, 0.f};

    half8 areg0, areg1, areg2;

#define A_ADDR(S, PTR, SCF) do {                                              \
    int k0_ = kbase + (S) * 32;                                               \
    if (k0_ < 3072) {                                                         \
        int t_ = k0_ / 768;                                                   \
        int rem_ = k0_ - t_ * 768;                                            \
        int sI_ = rem_ >> 8;                                                  \
        int d0_ = rem_ & 255;                                                 \
        PTR = fbase + t_ * 256 + d0_;                                         \
        SCF = (sI_ == 0) ? 1.0f : (sI_ == 1 ? s1v : s2v);                     \
    } else {                                                                  \
        PTR = xbase + (k0_ - 3072);                                           \
        SCF = 1.0f;                                                           \
    }                                                                         \
} while (0)

#define ALOAD(S, REG) do {                                                    \
    const _Float16* p_; float sc_;                                            \
    A_ADDR(S, p_, sc_);                                                       \
    REG = *(const half8*)p_;                                                  \
} while (0)

#define BSTAGE(BUF, S) do {                                                   \
    size_t koff_ = (size_t)(S) * 64;                                          \
    gload16(b_src[0] + koff_, (char*)(&sB[BUF][0]) + (0 * 64 + w * 16) * 64); \
    gload16(b_src[1] + koff_, (char*)(&sB[BUF][0]) + (1 * 64 + w * 16) * 64); \
} while (0)

#define AWRITE(BUF, S, REG) do {                                              \
    const _Float16* p_; float sc_;                                            \
    A_ADDR(S, p_, sc_);                                                       \
    half8 v_ = REG * (_Float16)sc_;                                           \
    *(half8*)(&sA[BUF][arow * 32 + aswz * 8]) = v_;                           \
} while (0)

#define COMPUTE(CB) do {                                                      \
    half8 af[4], bf[2];                                                       \
    _Pragma("unroll")                                                         \
    for (int rf = 0; rf < 4; rf++) af[rf] = *(const half8*)(&sA[CB][a_off[rf]]); \
    _Pragma("unroll")                                                         \
    for (int cf = 0; cf < 2; cf++) bf[cf] = *(const half8*)(&sB[CB][b_off[cf]]); \
    __builtin_amdgcn_s_setprio(1);                                            \
    _Pragma("unroll")                                                         \
    for (int rf = 0; rf < 4; rf++)                                            \
        _Pragma("unroll")                                                     \
        for (int cf = 0; cf < 2; cf++)                                        \
            acc[rf][cf] = __builtin_amdgcn_mfma_f32_16x16x32_f16(af[rf], bf[cf], acc[rf][cf], 0, 0, 0); \
    __builtin_amdgcn_s_setprio(0);                                            \
} while (0)

// one pipeline step: wait stage S arrived, publish A, barrier, prefetch S+2, compute
#define STEP(S, CBUF, AREG_C, NBUF, AREG_N) do {                              \
    asm volatile("s_waitcnt vmcnt(3)" ::: "memory");                          \
    AWRITE(CBUF, S, AREG_C);                                                  \
    asm volatile("s_waitcnt lgkmcnt(0)" ::: "memory");                        \
    __builtin_amdgcn_sched_barrier(0);                                        \
    __builtin_amdgcn_s_barrier();                                             \
    ALOAD((S) + 2, AREG_N);                                                   \
    BSTAGE(NBUF, (S) + 2);                                                    \
    COMPUTE(CBUF);                                                            \
} while (0)

    // prologue: stages 0,1 in flight (3 vm-ops each per wave)
    ALOAD(0, areg0); BSTAGE(0, 0);
    ALOAD(1, areg1); BSTAGE(1, 1);

    // steps 0..23 (8 triple-iterations, static buf/reg names; stages reach 25 exactly)
    int s = 0;
    for (int it = 0; it < 8; ++it, s += 3) {
        STEP(s + 0, 0, areg0, 2, areg2);
        STEP(s + 1, 1, areg1, 0, areg0);
        STEP(s + 2, 2, areg2, 1, areg1);
    }
    // step 24 (buf0): only stage 25 (3 ops) may remain in flight
    asm volatile("s_waitcnt vmcnt(3)" ::: "memory");
    AWRITE(0, 24, areg0);
    asm volatile("s_waitcnt lgkmcnt(0)" ::: "memory");
    __builtin_amdgcn_sched_barrier(0);
    __builtin_amdgcn_s_barrier();
    COMPUTE(0);
    // step 25 (buf1): drain
    asm volatile("s_waitcnt vmcnt(0)" ::: "memory");
    AWRITE(1, 25, areg1);
    asm volatile("s_waitcnt lgkmcnt(0)" ::: "memory");
    __builtin_amdgcn_sched_barrier(0);
    __builtin_amdgcn_s_barrier();
    COMPUTE(1);

#undef A_ADDR
#undef ALOAD
#undef BSTAGE
#undef AWRITE
#undef COMPUTE
#undef STEP

    // C/D layout: col = lane&15, row = (lane>>4)*4 + j ; wave covers local cols w*32..w*32+31
    _Float16* outb = hbuf + (size_t)ks * M_PAD * 256;
    #pragma unroll
    for (int rf = 0; rf < 4; rf++) {
        #pragma unroll
        for (int j = 0; j < 4; j++) {
            int grow = i0 + rf * 16 + kq * 4 + j;
            _Float16* orow = outb + (size_t)grow * 256 + n0 + w * 32;
            #pragma unroll
            for (int cf = 0; cf < 2; cf++)
                orow[cf * 16 + row_l] = (_Float16)acc[rf][cf][j];
        }
    }
}

// ---------------- 4-way reduce + bias + LN + relu + residual (+fp16 mirror) ----------------
__global__ void ln_kernel(const _Float16* __restrict__ hbuf, const float* __restrict__ xin,
                          const float* __restrict__ bvec, const float* __restrict__ gvec,
                          const float* __restrict__ evec, float* __restrict__ xout,
                          _Float16* __restrict__ xhout) {
    int wid = threadIdx.x >> 6, lane = threadIdx.x & 63;
    int row = blockIdx.x * 4 + wid;
    if (row >= N_NODES) return;
    const half4* p0 = (const half4*)(hbuf + (size_t)row * 256);
    const half4* p1 = (const half4*)(hbuf + (size_t)M_PAD * 256     + (size_t)row * 256);
    const half4* p2 = (const half4*)(hbuf + (size_t)M_PAD * 256 * 2 + (size_t)row * 256);
    const half4* p3 = (const half4*)(hbuf + (size_t)M_PAD * 256 * 3 + (size_t)row * 256);
    half4 h0 = p0[lane], h1 = p1[lane], h2 = p2[lane], h3 = p3[lane];
    float4 bv = ((const float4*)bvec)[lane];
    float4 hv;
    hv.x = (float)h0.x + (float)h1.x + (float)h2.x + (float)h3.x + bv.x;
    hv.y = (float)h0.y + (float)h1.y + (float)h2.y + (float)h3.y + bv.y;
    hv.z = (float)h0.z + (float)h1.z + (float)h2.z + (float)h3.z + bv.z;
    hv.w = (float)h0.w + (float)h1.w + (float)h2.w + (float)h3.w + bv.w;
    float s = hv.x + hv.y + hv.z + hv.w;
    float qsq = hv.x*hv.x + hv.y*hv.y + hv.z*hv.z + hv.w*hv.w;
    #pragma unroll
    for (int off = 1; off < 64; off <<= 1) {
        s   += __shfl_xor(s, off);
        qsq += __shfl_xor(qsq, off);
    }
    float mu  = s * (1.0f / 256.0f);
    float var = qsq * (1.0f / 256.0f) - mu * mu;
    float rs  = rsqrtf(var + EPS_LN);
    float4 g = ((const float4*)gvec)[lane];
    float4 e = ((const float4*)evec)[lane];
    float4 xv = ((const float4*)(xin + (size_t)row * 256))[lane];
    float4 o;
    o.x = fmaxf((hv.x - mu) * rs * g.x + e.x, 0.f) + xv.x;
    o.y = fmaxf((hv.y - mu) * rs * g.y + e.y, 0.f) + xv.y;
    o.z = fmaxf((hv.z - mu) * rs * g.z + e.z, 0.f) + xv.z;
    o.w = fmaxf((hv.w - mu) * rs * g.w + e.w, 0.f) + xv.w;
    ((float4*)(xout + (size_t)row * 256))[lane] = o;
    half4 oh = { (_Float16)o.x, (_Float16)o.y, (_Float16)o.z, (_Float16)o.w };
    ((half4*)(xhout + (size_t)row * 256))[lane] = oh;
}

// ---------------- final scoring ----------------
__global__ void score_kernel(const float* __restrict__ x, const float* __restrict__ remb,
                             const int* __restrict__ batch, float* __restrict__ out) {
    int wid = threadIdx.x >> 6, lane = threadIdx.x & 63;
    int g = blockIdx.x * 4 + wid;
    if (g >= B_BATCH * K_BATCH) return;
    int si = batch[g * 3 + 0], ri = batch[g * 3 + 1], ti = batch[g * 3 + 2];
    const float4* xs = (const float4*)(x + (size_t)si * 256);
    const float4* xr = (const float4*)(remb + (size_t)ri * 256);
    const float4* xt = (const float4*)(x + (size_t)ti * 256);
    float4 a = xs[lane], r = xr[lane], t = xt[lane];
    float p = a.x*r.x*t.x + a.y*r.y*t.y + a.z*r.z*t.z + a.w*r.w*t.w;
    #pragma unroll
    for (int off = 1; off < 64; off <<= 1) p += __shfl_xor(p, off);
    if (lane == 0) out[g] = p;
}

extern "C" void kernel_launch(void* const* d_in, const int* in_sizes, int n_in,
                              void* d_out, int out_size, void* d_ws, size_t ws_size,
                              hipStream_t stream) {
    const float* x_in     = (const float*)d_in[0];
    const float* rel_embs = (const float*)d_in[1];
    const float* Ws       = (const float*)d_in[2];
    const float* bs       = (const float*)d_in[3];
    const float* ln_s     = (const float*)d_in[4];
    const float* ln_b     = (const float*)d_in[5];
    const float* remb     = (const float*)d_in[6];
    const int*   eidx     = (const int*)d_in[7];
    const int*   etype    = (const int*)d_in[8];
    const int*   batch    = (const int*)d_in[9];
    float* out = (float*)d_out;

    char* wp = (char*)d_ws;
    size_t o = 0;
    auto alloc = [&](size_t bytes) { void* p = wp + o; o += (bytes + 255) & ~255ull; return p; };
    int*      deg_in  = (int*)     alloc((size_t)N_NODES * 4);
    int*      offs    = (int*)     alloc((size_t)N_NODES * 4);
    int*      cursor  = (int*)     alloc((size_t)N_NODES * 4);
    float*    s1      = (float*)   alloc((size_t)M_PAD * 4);
    float*    s2      = (float*)   alloc((size_t)M_PAD * 4);
    float*    sum_log = (float*)   alloc(256);
    int*      csr_src = (int*)     alloc((size_t)E_EDGES * 4);
    int*      csr_et  = (int*)     alloc((size_t)E_EDGES * 4);
    _Float16* feats   = (_Float16*)alloc((size_t)M_PAD * 1024 * 2);           // 20.6 MB
    _Float16* Wt      = (_Float16*)alloc((size_t)L_LAYERS * 256 * K13 * 2);   // 10.2 MB
    _Float16* hbuf    = (_Float16*)alloc((size_t)KSPLIT * M_PAD * 256 * 2);   // 20.6 MB
    float*    xb0     = (float*)   alloc((size_t)M_PAD * 256 * 4);
    float*    xb1     = (float*)   alloc((size_t)M_PAD * 256 * 4);
    _Float16* xh0     = (_Float16*)alloc((size_t)M_PAD * 256 * 2);
    _Float16* xh1     = (_Float16*)alloc((size_t)M_PAD * 256 * 2);
    _Float16* relh    = (_Float16*)alloc((size_t)L_LAYERS * R_REL * 256 * 2); // 0.73 MB

    const int* src  = eidx;
    const int* dstp = eidx + E_EDGES;

    hipMemsetAsync(deg_in, 0, (size_t)N_NODES * 4, stream);
    hist_kernel<<<(E_EDGES + 255) / 256, 256, 0, stream>>>(dstp, deg_in);
    scan_kernel<<<1, 1024, 0, stream>>>(deg_in, offs, cursor, sum_log);
    fill_kernel<<<(E_EDGES + 255) / 256, 256, 0, stream>>>(src, dstp, etype, cursor, csr_src, csr_et);
    scales_kernel<<<(N_NODES + 255) / 256, 256, 0, stream>>>(deg_in, sum_log, s1, s2);
    {
        const int TOT = L_LAYERS * 256 * K13;
        wt_kernel<<<(TOT + 255) / 256, 256, 0, stream>>>(Ws, Wt);
        const int RT = L_LAYERS * R_REL * 256;
        cvt_kernel<<<(RT + 255) / 256, 256, 0, stream>>>(rel_embs, relh, RT);
        const int XT = N_NODES * 256;
        cvt_kernel<<<(XT + 255) / 256, 256, 0, stream>>>(x_in, xh0, XT);
    }
    hipMemcpyAsync(xb0, x_in, (size_t)N_NODES * 256 * 4, hipMemcpyDeviceToDevice, stream);

    float* xc = xb0; float* xn = xb1;
    _Float16* xhc = xh0; _Float16* xhn = xh1;
    for (int l = 0; l < L_LAYERS; l++) {
        agg_kernel<<<(N_NODES + 3) / 4, 256, 0, stream>>>(
            xc, xhc, relh + (size_t)l * R_REL * 256,
            offs, deg_in, csr_src, csr_et, feats);
        gemm_kernel<<<1256, 256, 0, stream>>>(
            feats, xhc, Wt + (size_t)l * 256 * K13, s1, s2, hbuf);
        ln_kernel<<<(N_NODES + 3) / 4, 256, 0, stream>>>(
            hbuf, xc, bs + (size_t)l * 256, ln_s + (size_t)l * 256, ln_b + (size_t)l * 256, xn, xhn);
        float* t = xc; xc = xn; xn = t;
        _Float16* th = xhc; xhc = xhn; xhn = th;
    }
    score_kernel<<<(B_BATCH * K_BATCH + 3) / 4, 256, 0, stream>>>(xc, remb, batch, out);
}

// Round 9
// 505.613 us; speedup vs baseline: 10.7286x; 1.0677x over previous
//
#include <hip/hip_runtime.h>
#include <math.h>

typedef __attribute__((ext_vector_type(8))) _Float16 half8;
typedef __attribute__((ext_vector_type(4))) _Float16 half4;
typedef __attribute__((ext_vector_type(4))) float    floatx4;

#define N_NODES 10000
#define M_PAD   10112      // 79 * 128
#define MTILES  79
#define E_EDGES 160000
#define DIM     256
#define R_REL   237
#define L_LAYERS 6
#define B_BATCH 128
#define K_BATCH 33
#define K13     3328       // 13*256
#define KSPLIT  4
#define KSLICE  832        // K13/KSPLIT (halves)
#define KS_STEPS 26        // KSLICE/32
#define EPS_STD 1e-6f
#define EPS_LN  1e-5f

// async global->LDS, 16B per lane; LDS dest = wave-uniform base + lane*16
__device__ __forceinline__ void gload16(const void* g, void* lds) {
    __builtin_amdgcn_global_load_lds(
        (const __attribute__((address_space(1))) unsigned int*)g,
        (__attribute__((address_space(3))) unsigned int*)lds, 16, 0, 0);
}

// ---------------- CSR build ----------------
__global__ void hist_kernel(const int* __restrict__ dst, int* __restrict__ deg) {
    int e = blockIdx.x * blockDim.x + threadIdx.x;
    if (e < E_EDGES) atomicAdd(&deg[dst[e]], 1);
}

__global__ void scan_kernel(const int* __restrict__ deg_in, int* __restrict__ offs,
                            int* __restrict__ cursor, float* __restrict__ sum_log) {
    __shared__ int   part[1024];
    __shared__ float slog[1024];
    int t = threadIdx.x;
    const int CH = 10;
    int base = t * CH;
    int lsum = 0; float ls = 0.f;
    for (int j = 0; j < CH; j++) {
        int i = base + j;
        if (i < N_NODES) { int d = deg_in[i]; lsum += d; ls += logf((float)(d + 1)); }
    }
    part[t] = lsum; slog[t] = ls;
    __syncthreads();
    for (int off = 1; off < 1024; off <<= 1) {
        int v = (t >= off) ? part[t - off] : 0;
        __syncthreads();
        part[t] += v;
        __syncthreads();
    }
    int run = part[t] - lsum;
    for (int j = 0; j < CH; j++) {
        int i = base + j;
        if (i < N_NODES) { offs[i] = run; cursor[i] = run; run += deg_in[i]; }
    }
    __syncthreads();
    for (int off = 512; off > 0; off >>= 1) {
        if (t < off) slog[t] += slog[t + off];
        __syncthreads();
    }
    if (t == 0) sum_log[0] = slog[0];
}

__global__ void fill_kernel(const int* __restrict__ src, const int* __restrict__ dst,
                            const int* __restrict__ et, int* __restrict__ cursor,
                            int* __restrict__ csr_src, int* __restrict__ csr_et) {
    int e = blockIdx.x * blockDim.x + threadIdx.x;
    if (e < E_EDGES) {
        int d = dst[e];
        int p = atomicAdd(&cursor[d], 1);
        csr_src[p] = src[e];
        csr_et[p]  = et[e];
    }
}

__global__ void scales_kernel(const int* __restrict__ deg_in, const float* __restrict__ sum_log,
                              float* __restrict__ s1, float* __restrict__ s2) {
    int i = blockIdx.x * blockDim.x + threadIdx.x;
    if (i < N_NODES) {
        float mean = sum_log[0] * (1.0f / (float)N_NODES);
        float sc = logf((float)(deg_in[i] + 1)) / mean;
        s1[i] = sc;
        s2[i] = 1.0f / fmaxf(sc, 0.01f);
    }
}

// -------- W permute+transpose to fp16: Wt[l][n][k'] = W[l][korig(k')][n] --------
// new A col order: k' = t*768 + s*256 + d, x at 3072+; korig = (t*256+d)*3 + s
__global__ void wt_kernel(const float* __restrict__ Ws, _Float16* __restrict__ Wt) {
    int idx = blockIdx.x * 256 + threadIdx.x;
    const int TOT = L_LAYERS * 256 * K13;
    if (idx >= TOT) return;
    int l = idx / (256 * K13);
    int r = idx - l * (256 * K13);
    int n = r / K13, k = r - n * K13;
    int korig;
    if (k < 3072) {
        int t = k / 768;
        int rem = k - t * 768;
        int s = rem >> 8;
        int d = rem & 255;
        korig = (t * 256 + d) * 3 + s;
    } else {
        korig = k;
    }
    Wt[idx] = (_Float16)Ws[(size_t)l * K13 * 256 + (size_t)korig * 256 + n];
}

// -------- fp32 -> fp16 converter --------
__global__ void cvt_kernel(const float* __restrict__ in, _Float16* __restrict__ outp, int n) {
    int i = blockIdx.x * 256 + threadIdx.x;
    if (i < n) outp[i] = (_Float16)in[i];
}

// ---- aggregation: one wave per node, 2 edges/iteration (lane halves), fp16 gather ----
__global__ void agg_kernel(const float* __restrict__ x, const _Float16* __restrict__ xh,
                           const _Float16* __restrict__ relh,
                           const int* __restrict__ offs, const int* __restrict__ deg_in,
                           const int* __restrict__ csr_src, const int* __restrict__ csr_et,
                           _Float16* __restrict__ feats) {
    int wid  = threadIdx.x >> 6;
    int lane = threadIdx.x & 63;
    int node = blockIdx.x * 4 + wid;
    if (node >= N_NODES) return;
    int half = lane >> 5;
    int sub  = lane & 31;
    int off = offs[node];
    int end = off + deg_in[node];
    const half8* xh8 = (const half8*)xh;
    const half8* rh8 = (const half8*)relh;

    float s_[8], q_[8], mx_[8], mn_[8];
    #pragma unroll
    for (int i = 0; i < 8; i++) { s_[i] = 0.f; q_[i] = 0.f; mx_[i] = -INFINITY; mn_[i] = INFINITY; }

    for (int base = off; base < end; base += 2) {
        int e = base + half;
        if (e < end) {
            int sN = csr_src[e];
            int et = csr_et[e];
            half8 xv = xh8[(size_t)sN * 32 + sub];
            half8 rv = rh8[(size_t)et * 32 + sub];
            #pragma unroll
            for (int i = 0; i < 8; i++) {
                float m = (float)xv[i] * (float)rv[i];
                s_[i] += m; q_[i] += m * m;
                mx_[i] = fmaxf(mx_[i], m);
                mn_[i] = fminf(mn_[i], m);
            }
        }
    }
    #pragma unroll
    for (int i = 0; i < 8; i++) {
        s_[i] += __shfl_xor(s_[i], 32);
        q_[i] += __shfl_xor(q_[i], 32);
        mx_[i] = fmaxf(mx_[i], __shfl_xor(mx_[i], 32));
        mn_[i] = fminf(mn_[i], __shfl_xor(mn_[i], 32));
    }
    const float4* xrow = (const float4*)(x + (size_t)node * 256);
    float4 xa = xrow[sub * 2], xb = xrow[sub * 2 + 1];
    float xs[8] = {xa.x, xa.y, xa.z, xa.w, xb.x, xb.y, xb.z, xb.w};
    #pragma unroll
    for (int i = 0; i < 8; i++) {
        s_[i] += xs[i]; q_[i] += xs[i] * xs[i];
        mx_[i] = fmaxf(mx_[i], xs[i]);
        mn_[i] = fminf(mn_[i], xs[i]);
    }
    float inv = 1.0f / (float)(end - off + 1);
    half8 hm, hx, hn, hs;
    #pragma unroll
    for (int i = 0; i < 8; i++) {
        float mean = s_[i] * inv;
        float sd = sqrtf(fmaxf(q_[i] * inv - mean * mean, EPS_STD));
        hm[i] = (_Float16)mean; hx[i] = (_Float16)mx_[i];
        hn[i] = (_Float16)mn_[i]; hs[i] = (_Float16)sd;
    }
    half8* fout = (half8*)(feats + (size_t)node * 1024);
    if (half == 0) {
        fout[0 * 32 + sub] = hm;
        fout[1 * 32 + sub] = hx;
    } else {
        fout[2 * 32 + sub] = hn;
        fout[3 * 32 + sub] = hs;
    }
}

// ---------------- fp16 MFMA GEMM: 128x128 tiles, 2x2 waves (64x64 each), 3-buf counted-vmcnt ----
// grid = 79 m * 2 nh * 4 ks = 632 = 8*79 (exact XCD swizzle); 48 KB LDS -> 3 blocks/CU
__launch_bounds__(256, 3)
__global__ void gemm_kernel(const _Float16* __restrict__ feats, const _Float16* __restrict__ xh,
                            const _Float16* __restrict__ Wt, const float* __restrict__ s1a,
                            const float* __restrict__ s2a, _Float16* __restrict__ hbuf) {
    __shared__ _Float16 sA[3][128 * 32];   // 24 KB
    __shared__ _Float16 sB[3][128 * 32];   // 24 KB

    // XCD swizzle: 632 = 8*79; each XCD owns one (ks,nh) pair -> B slice L2-resident
    int xcd = blockIdx.x & 7, loc = blockIdx.x >> 3;
    int lin = xcd * MTILES + loc;
    int ks  = lin / (2 * MTILES);
    int rem = lin - ks * (2 * MTILES);
    int nh  = rem / MTILES;
    int m   = rem - nh * MTILES;
    const int i0    = m * 128;
    const int n0    = nh * 128;
    const int kbase = ks * KSLICE;

    const int tid   = threadIdx.x;
    const int lane  = tid & 63;
    const int w     = tid >> 6;
    const int wr    = w >> 1;               // wave row 0..1
    const int wc    = w & 1;                // wave col 0..1
    const int row_l = lane & 15;
    const int kq    = lane >> 4;

    // reader LDS offsets (halves), XOR chunk swizzle: chunk' = chunk ^ ((row>>1)&3)
    int a_off[4], b_off[4];
    #pragma unroll
    for (int rf = 0; rf < 4; rf++) {
        int r = wr * 64 + rf * 16 + row_l;
        a_off[rf] = r * 32 + ((kq ^ ((r >> 1) & 3)) & 3) * 8;
    }
    #pragma unroll
    for (int cf = 0; cf < 4; cf++) {
        int n_ = wc * 64 + cf * 16 + row_l;
        b_off[cf] = n_ * 32 + ((kq ^ ((n_ >> 1) & 3)) & 3) * 8;
    }

    // ---- A staging: thread -> rows (arow, arow+64), k-chunk ac; swizzled LDS slot ----
    const int arow = tid >> 2;               // 0..63
    const int ac   = tid & 3;
    const int aswz = ac ^ ((arow >> 1) & 3); // same for arow+64 (bit pattern +32 ≡ 0 mod 4)
    const float s1lo = s1a[i0 + arow],      s2lo = s2a[i0 + arow];
    const float s1hi = s1a[i0 + arow + 64], s2hi = s2a[i0 + arow + 64];
    const _Float16* fb_lo = feats + (size_t)(i0 + arow) * 1024 + ac * 8;
    const _Float16* xb_lo = xh    + (size_t)(i0 + arow) * 256  + ac * 8;
    const _Float16* fb_hi = fb_lo + (size_t)64 * 1024;
    const _Float16* xb_hi = xb_lo + (size_t)64 * 256;

    // ---- B staging: 128 rows, 2 gload16 per wave; pre-swizzled source, linear dest ----
    const char* b_src[2];
    #pragma unroll
    for (int j = 0; j < 2; j++) {
        int rloc = j * 64 + w * 16 + (lane >> 2);
        int c = (lane & 3) ^ ((rloc >> 1) & 3);
        b_src[j] = (const char*)(Wt + (size_t)(n0 + rloc) * K13 + kbase + c * 8);
    }

    floatx4 acc[4][4];
    #pragma unroll
    for (int rf = 0; rf < 4; rf++)
        #pragma unroll
        for (int cf = 0; cf < 4; cf++)
            acc[rf][cf] = (floatx4){0.f, 0.f, 0.f, 0.f};

    half8 a0lo, a0hi, a1lo, a1hi, a2lo, a2hi;

#define A_OFS(S, OFS, SCL, SCH) do {                                          \
    int k0_ = kbase + (S) * 32;                                               \
    if (k0_ < 3072) {                                                         \
        int t_ = k0_ / 768;                                                   \
        int rem_ = k0_ - t_ * 768;                                            \
        int sI_ = rem_ >> 8;                                                  \
        OFS = t_ * 256 + (rem_ & 255);                                        \
        SCL = (sI_ == 0) ? 1.0f : (sI_ == 1 ? s1lo : s2lo);                   \
        SCH = (sI_ == 0) ? 1.0f : (sI_ == 1 ? s1hi : s2hi);                   \
    } else {                                                                  \
        OFS = -(k0_ - 3072) - 1;                                              \
        SCL = 1.0f; SCH = 1.0f;                                               \
    }                                                                         \
} while (0)

#define ALOAD(S, RLO, RHI) do {                                               \
    int ofs_; float scl_, sch_;                                               \
    A_OFS(S, ofs_, scl_, sch_);                                               \
    if (ofs_ >= 0) { RLO = *(const half8*)(fb_lo + ofs_);                     \
                     RHI = *(const half8*)(fb_hi + ofs_); }                   \
    else           { RLO = *(const half8*)(xb_lo + (-ofs_ - 1));              \
                     RHI = *(const half8*)(xb_hi + (-ofs_ - 1)); }            \
} while (0)

#define BSTAGE(BUF, S) do {                                                   \
    size_t koff_ = (size_t)(S) * 64;                                          \
    gload16(b_src[0] + koff_, (char*)(&sB[BUF][0]) + (0 * 64 + w * 16) * 64); \
    gload16(b_src[1] + koff_, (char*)(&sB[BUF][0]) + (1 * 64 + w * 16) * 64); \
} while (0)

#define AWRITE(BUF, S, RLO, RHI) do {                                         \
    int ofs_; float scl_, sch_;                                               \
    A_OFS(S, ofs_, scl_, sch_);                                               \
    half8 vl_ = RLO * (_Float16)scl_;                                         \
    half8 vh_ = RHI * (_Float16)sch_;                                         \
    *(half8*)(&sA[BUF][arow * 32 + aswz * 8]) = vl_;                          \
    *(half8*)(&sA[BUF][(arow + 64) * 32 + aswz * 8]) = vh_;                   \
} while (0)

#define COMPUTE(CB) do {                                                      \
    half8 af[4], bf[4];                                                       \
    _Pragma("unroll")                                                         \
    for (int rf = 0; rf < 4; rf++) af[rf] = *(const half8*)(&sA[CB][a_off[rf]]); \
    _Pragma("unroll")                                                         \
    for (int cf = 0; cf < 4; cf++) bf[cf] = *(const half8*)(&sB[CB][b_off[cf]]); \
    __builtin_amdgcn_s_setprio(1);                                            \
    _Pragma("unroll")                                                         \
    for (int rf = 0; rf < 4; rf++)                                            \
        _Pragma("unroll")                                                     \
        for (int cf = 0; cf < 4; cf++)                                        \
            acc[rf][cf] = __builtin_amdgcn_mfma_f32_16x16x32_f16(af[rf], bf[cf], acc[rf][cf], 0, 0, 0); \
    __builtin_amdgcn_s_setprio(0);                                            \
} while (0)

// one pipeline step: wait stage S arrived (vmcnt(4): stage S+1's 4 ops may remain),
// publish A, barrier, prefetch S+2, compute
#define STEP(S, CBUF, ALO, AHI, NBUF, NLO, NHI) do {                          \
    asm volatile("s_waitcnt vmcnt(4)" ::: "memory");                          \
    AWRITE(CBUF, S, ALO, AHI);                                                \
    asm volatile("s_waitcnt lgkmcnt(0)" ::: "memory");                        \
    __builtin_amdgcn_sched_barrier(0);                                        \
    __builtin_amdgcn_s_barrier();                                             \
    ALOAD((S) + 2, NLO, NHI);                                                 \
    BSTAGE(NBUF, (S) + 2);                                                    \
    COMPUTE(CBUF);                                                            \
} while (0)

    // prologue: stages 0,1 in flight (4 vm-ops each per wave: 2 A-reg + 2 B-lds)
    ALOAD(0, a0lo, a0hi); BSTAGE(0, 0);
    ALOAD(1, a1lo, a1hi); BSTAGE(1, 1);

    // steps 0..23 (8 triple-iterations; prefetch reaches stage 25 exactly)
    int s = 0;
    for (int it = 0; it < 8; ++it, s += 3) {
        STEP(s + 0, 0, a0lo, a0hi, 2, a2lo, a2hi);
        STEP(s + 1, 1, a1lo, a1hi, 0, a0lo, a0hi);
        STEP(s + 2, 2, a2lo, a2hi, 1, a1lo, a1hi);
    }
    // step 24 (buf0): only stage 25 (4 ops) may remain in flight
    asm volatile("s_waitcnt vmcnt(4)" ::: "memory");
    AWRITE(0, 24, a0lo, a0hi);
    asm volatile("s_waitcnt lgkmcnt(0)" ::: "memory");
    __builtin_amdgcn_sched_barrier(0);
    __builtin_amdgcn_s_barrier();
    COMPUTE(0);
    // step 25 (buf1): drain
    asm volatile("s_waitcnt vmcnt(0)" ::: "memory");
    AWRITE(1, 25, a1lo, a1hi);
    asm volatile("s_waitcnt lgkmcnt(0)" ::: "memory");
    __builtin_amdgcn_sched_barrier(0);
    __builtin_amdgcn_s_barrier();
    COMPUTE(1);

#undef A_OFS
#undef ALOAD
#undef BSTAGE
#undef AWRITE
#undef COMPUTE
#undef STEP

    // C/D layout: col = lane&15, row = (lane>>4)*4 + j ; wave tile (wr*64, wc*64)
    _Float16* outb = hbuf + (size_t)ks * M_PAD * 256;
    #pragma unroll
    for (int rf = 0; rf < 4; rf++) {
        #pragma unroll
        for (int j = 0; j < 4; j++) {
            int grow = i0 + wr * 64 + rf * 16 + kq * 4 + j;
            _Float16* orow = outb + (size_t)grow * 256 + n0 + wc * 64;
            #pragma unroll
            for (int cf = 0; cf < 4; cf++)
                orow[cf * 16 + row_l] = (_Float16)acc[rf][cf][j];
        }
    }
}

// ---------------- 4-way reduce + bias + LN + relu + residual (+fp16 mirror) ----------------
__global__ void ln_kernel(const _Float16* __restrict__ hbuf, const float* __restrict__ xin,
                          const float* __restrict__ bvec, const float* __restrict__ gvec,
                          const float* __restrict__ evec, float* __restrict__ xout,
                          _Float16* __restrict__ xhout) {
    int wid = threadIdx.x >> 6, lane = threadIdx.x & 63;
    int row = blockIdx.x * 4 + wid;
    if (row >= N_NODES) return;
    const half4* p0 = (const half4*)(hbuf + (size_t)row * 256);
    const half4* p1 = (const half4*)(hbuf + (size_t)M_PAD * 256     + (size_t)row * 256);
    const half4* p2 = (const half4*)(hbuf + (size_t)M_PAD * 256 * 2 + (size_t)row * 256);
    const half4* p3 = (const half4*)(hbuf + (size_t)M_PAD * 256 * 3 + (size_t)row * 256);
    half4 h0 = p0[lane], h1 = p1[lane], h2 = p2[lane], h3 = p3[lane];
    float4 bv = ((const float4*)bvec)[lane];
    float4 hv;
    hv.x = (float)h0.x + (float)h1.x + (float)h2.x + (float)h3.x + bv.x;
    hv.y = (float)h0.y + (float)h1.y + (float)h2.y + (float)h3.y + bv.y;
    hv.z = (float)h0.z + (float)h1.z + (float)h2.z + (float)h3.z + bv.z;
    hv.w = (float)h0.w + (float)h1.w + (float)h2.w + (float)h3.w + bv.w;
    float s = hv.x + hv.y + hv.z + hv.w;
    float qsq = hv.x*hv.x + hv.y*hv.y + hv.z*hv.z + hv.w*hv.w;
    #pragma unroll
    for (int off = 1; off < 64; off <<= 1) {
        s   += __shfl_xor(s, off);
        qsq += __shfl_xor(qsq, off);
    }
    float mu  = s * (1.0f / 256.0f);
    float var = qsq * (1.0f / 256.0f) - mu * mu;
    float rs  = rsqrtf(var + EPS_LN);
    float4 g = ((const float4*)gvec)[lane];
    float4 e = ((const float4*)evec)[lane];
    float4 xv = ((const float4*)(xin + (size_t)row * 256))[lane];
    float4 o;
    o.x = fmaxf((hv.x - mu) * rs * g.x + e.x, 0.f) + xv.x;
    o.y = fmaxf((hv.y - mu) * rs * g.y + e.y, 0.f) + xv.y;
    o.z = fmaxf((hv.z - mu) * rs * g.z + e.z, 0.f) + xv.z;
    o.w = fmaxf((hv.w - mu) * rs * g.w + e.w, 0.f) + xv.w;
    ((float4*)(xout + (size_t)row * 256))[lane] = o;
    half4 oh = { (_Float16)o.x, (_Float16)o.y, (_Float16)o.z, (_Float16)o.w };
    ((half4*)(xhout + (size_t)row * 256))[lane] = oh;
}

// ---------------- final scoring ----------------
__global__ void score_kernel(const float* __restrict__ x, const float* __restrict__ remb,
                             const int* __restrict__ batch, float* __restrict__ out) {
    int wid = threadIdx.x >> 6, lane = threadIdx.x & 63;
    int g = blockIdx.x * 4 + wid;
    if (g >= B_BATCH * K_BATCH) return;
    int si = batch[g * 3 + 0], ri = batch[g * 3 + 1], ti = batch[g * 3 + 2];
    const float4* xs = (const float4*)(x + (size_t)si * 256);
    const float4* xr = (const float4*)(remb + (size_t)ri * 256);
    const float4* xt = (const float4*)(x + (size_t)ti * 256);
    float4 a = xs[lane], r = xr[lane], t = xt[lane];
    float p = a.x*r.x*t.x + a.y*r.y*t.y + a.z*r.z*t.z + a.w*r.w*t.w;
    #pragma unroll
    for (int off = 1; off < 64; off <<= 1) p += __shfl_xor(p, off);
    if (lane == 0) out[g] = p;
}

extern "C" void kernel_launch(void* const* d_in, const int* in_sizes, int n_in,
                              void* d_out, int out_size, void* d_ws, size_t ws_size,
                              hipStream_t stream) {
    const float* x_in     = (const float*)d_in[0];
    const float* rel_embs = (const float*)d_in[1];
    const float* Ws       = (const float*)d_in[2];
    const float* bs       = (const float*)d_in[3];
    const float* ln_s     = (const float*)d_in[4];
    const float* ln_b     = (const float*)d_in[5];
    const float* remb     = (const float*)d_in[6];
    const int*   eidx     = (const int*)d_in[7];
    const int*   etype    = (const int*)d_in[8];
    const int*   batch    = (const int*)d_in[9];
    float* out = (float*)d_out;

    char* wp = (char*)d_ws;
    size_t o = 0;
    auto alloc = [&](size_t bytes) { void* p = wp + o; o += (bytes + 255) & ~255ull; return p; };
    int*      deg_in  = (int*)     alloc((size_t)N_NODES * 4);
    int*      offs    = (int*)     alloc((size_t)N_NODES * 4);
    int*      cursor  = (int*)     alloc((size_t)N_NODES * 4);
    float*    s1      = (float*)   alloc((size_t)M_PAD * 4);
    float*    s2      = (float*)   alloc((size_t)M_PAD * 4);
    float*    sum_log = (float*)   alloc(256);
    int*      csr_src = (int*)     alloc((size_t)E_EDGES * 4);
    int*      csr_et  = (int*)     alloc((size_t)E_EDGES * 4);
    _Float16* feats   = (_Float16*)alloc((size_t)M_PAD * 1024 * 2);           // 20.7 MB
    _Float16* Wt      = (_Float16*)alloc((size_t)L_LAYERS * 256 * K13 * 2);   // 10.2 MB
    _Float16* hbuf    = (_Float16*)alloc((size_t)KSPLIT * M_PAD * 256 * 2);   // 20.7 MB
    float*    xb0     = (float*)   alloc((size_t)M_PAD * 256 * 4);
    float*    xb1     = (float*)   alloc((size_t)M_PAD * 256 * 4);
    _Float16* xh0     = (_Float16*)alloc((size_t)M_PAD * 256 * 2);
    _Float16* xh1     = (_Float16*)alloc((size_t)M_PAD * 256 * 2);
    _Float16* relh    = (_Float16*)alloc((size_t)L_LAYERS * R_REL * 256 * 2); // 0.73 MB

    const int* src  = eidx;
    const int* dstp = eidx + E_EDGES;

    hipMemsetAsync(deg_in, 0, (size_t)N_NODES * 4, stream);
    hist_kernel<<<(E_EDGES + 255) / 256, 256, 0, stream>>>(dstp, deg_in);
    scan_kernel<<<1, 1024, 0, stream>>>(deg_in, offs, cursor, sum_log);
    fill_kernel<<<(E_EDGES + 255) / 256, 256, 0, stream>>>(src, dstp, etype, cursor, csr_src, csr_et);
    scales_kernel<<<(N_NODES + 255) / 256, 256, 0, stream>>>(deg_in, sum_log, s1, s2);
    {
        const int TOT = L_LAYERS * 256 * K13;
        wt_kernel<<<(TOT + 255) / 256, 256, 0, stream>>>(Ws, Wt);
        const int RT = L_LAYERS * R_REL * 256;
        cvt_kernel<<<(RT + 255) / 256, 256, 0, stream>>>(rel_embs, relh, RT);
        const int XT = N_NODES * 256;
        cvt_kernel<<<(XT + 255) / 256, 256, 0, stream>>>(x_in, xh0, XT);
    }
    hipMemcpyAsync(xb0, x_in, (size_t)N_NODES * 256 * 4, hipMemcpyDeviceToDevice, stream);

    float* xc = xb0; float* xn = xb1;
    _Float16* xhc = xh0; _Float16* xhn = xh1;
    for (int l = 0; l < L_LAYERS; l++) {
        agg_kernel<<<(N_NODES + 3) / 4, 256, 0, stream>>>(
            xc, xhc, relh + (size_t)l * R_REL * 256,
            offs, deg_in, csr_src, csr_et, feats);
        gemm_kernel<<<632, 256, 0, stream>>>(
            feats, xhc, Wt + (size_t)l * 256 * K13, s1, s2, hbuf);
        ln_kernel<<<(N_NODES + 3) / 4, 256, 0, stream>>>(
            hbuf, xc, bs + (size_t)l * 256, ln_s + (size_t)l * 256, ln_b + (size_t)l * 256, xn, xhn);
        float* t = xc; xc = xn; xn = t;
        _Float16* th = xhc; xhc = xhn; xhn = th;
    }
    score_kernel<<<(B_BATCH * K_BATCH + 3) / 4, 256, 0, stream>>>(xc, remb, batch, out);
}